// Round 1
// baseline (2954.586 us; speedup 1.0000x reference)
//
#include <hip/hip_runtime.h>

#define NN 50000
#define NE 600000
#define IND 64
#define HID 128
#define NREL 10
#define NLAY 6
#define NG 64
#define LN_EPS 1e-5f

// ---------------------------------------------------------------- utilities
__global__ void zero_kernel(float* __restrict__ p, int n) {
  int i = blockIdx.x * blockDim.x + threadIdx.x;
  int stride = gridDim.x * blockDim.x;
  for (; i < n; i += stride) p[i] = 0.f;
}

__global__ void count_edges(const int* __restrict__ dst, const int* __restrict__ et,
                            float* __restrict__ winv, int* __restrict__ deg) {
  int e = blockIdx.x * 256 + threadIdx.x;
  if (e >= NE) return;
  int d = dst[e];
  atomicAdd(&winv[d * NREL + et[e]], 1.0f);
  atomicAdd(&deg[d], 1);
}

__global__ void invert_winv(float* __restrict__ winv) {
  int i = blockIdx.x * 256 + threadIdx.x;
  if (i < NN * NREL) winv[i] = 1.0f / fmaxf(winv[i], 1.0f);
}

// Hillis-Steele inclusive scan per 256-block; writes exclusive prefix + block sums
__global__ void scan_block(const int* __restrict__ deg, int* __restrict__ rowstart,
                           int* __restrict__ partial) {
  __shared__ int sh[256];
  int i = blockIdx.x * 256 + threadIdx.x;
  int v = (i < NN) ? deg[i] : 0;
  sh[threadIdx.x] = v;
  __syncthreads();
  int x = v;
  for (int off = 1; off < 256; off <<= 1) {
    int y = (threadIdx.x >= off) ? sh[threadIdx.x - off] : 0;
    __syncthreads();
    x += y;
    sh[threadIdx.x] = x;
    __syncthreads();
  }
  if (i < NN) rowstart[i] = x - v;  // block-local exclusive
  if (threadIdx.x == 255) partial[blockIdx.x] = x;
}

__global__ void scan_partials(int* __restrict__ partial, int nb) {
  __shared__ int sh[256];
  int v = (threadIdx.x < nb) ? partial[threadIdx.x] : 0;
  sh[threadIdx.x] = v;
  __syncthreads();
  int x = v;
  for (int off = 1; off < 256; off <<= 1) {
    int y = (threadIdx.x >= off) ? sh[threadIdx.x - off] : 0;
    __syncthreads();
    x += y;
    sh[threadIdx.x] = x;
    __syncthreads();
  }
  partial[threadIdx.x] = x - v;  // exclusive
}

__global__ void scan_add(int* __restrict__ rowstart, const int* __restrict__ partial) {
  int i = blockIdx.x * 256 + threadIdx.x;
  if (i < NN) rowstart[i] += partial[i >> 8];
  if (i == 0) rowstart[NN] = NE;
}

__global__ void fill_eids(const int* __restrict__ dst, int* __restrict__ fillpos,
                          const int* __restrict__ rowstart, int* __restrict__ eids) {
  int e = blockIdx.x * 256 + threadIdx.x;
  if (e >= NE) return;
  int d = dst[e];
  int pos = rowstart[d] + atomicAdd(&fillpos[d], 1);
  eids[pos] = e;
}

// ---------------------------------------------------------------- fp32 GEMM
// C[M x N] = A[M x K] @ B  (+bias). B is addressed in 128-wide column blocks:
// addr = B + (ncol>>7)*bstride + k*ldb + (ncol&127)  -> handles rel_w [r][k][o]
// without repacking. BM=BN=64, BK=32, 256 threads, 4x4 per thread.
#define BM 64
#define BN 64
#define BK 32

__global__ __launch_bounds__(256) void gemm_f32(
    const float* __restrict__ A, const float* __restrict__ B,
    const float* __restrict__ bias, float* __restrict__ C,
    int M, int K, int ldb, long bstride, int ldc) {
  __shared__ float As[BK][BM + 4];  // transposed, padded (16B-aligned rows)
  __shared__ float Bs[BK][BN];
  const int tid = threadIdx.x;
  const int bm = blockIdx.y * BM;
  const int bn = blockIdx.x * BN;
  const float* Bblk = B + (long)(bn >> 7) * bstride + (bn & 127);

  const int rA = tid >> 3;         // 0..31
  const int cA = (tid & 7) * 4;    // 0..28
  const int rB = tid >> 4;         // 0..15
  const int cB = (tid & 15) * 4;   // 0..60
  const int tm = (tid >> 4) * 4;   // 0..60
  const int tn = (tid & 15) * 4;   // 0..60

  float acc[4][4] = {};

  for (int k0 = 0; k0 < K; k0 += BK) {
#pragma unroll
    for (int rr = 0; rr < 2; ++rr) {
      int row = bm + rA + rr * 32;
      float4 av = make_float4(0.f, 0.f, 0.f, 0.f);
      if (row < M) av = *(const float4*)(A + (long)row * K + k0 + cA);
      As[cA + 0][rA + rr * 32] = av.x;
      As[cA + 1][rA + rr * 32] = av.y;
      As[cA + 2][rA + rr * 32] = av.z;
      As[cA + 3][rA + rr * 32] = av.w;
    }
#pragma unroll
    for (int rr = 0; rr < 2; ++rr) {
      int krow = k0 + rB + rr * 16;
      *(float4*)&Bs[rB + rr * 16][cB] = *(const float4*)(Bblk + (long)krow * ldb + cB);
    }
    __syncthreads();
#pragma unroll
    for (int kk = 0; kk < BK; ++kk) {
      float4 a4 = *(const float4*)&As[kk][tm];
      float4 b4 = *(const float4*)&Bs[kk][tn];
      float a[4] = {a4.x, a4.y, a4.z, a4.w};
      float b[4] = {b4.x, b4.y, b4.z, b4.w};
#pragma unroll
      for (int i = 0; i < 4; ++i)
#pragma unroll
        for (int j = 0; j < 4; ++j) acc[i][j] += a[i] * b[j];
    }
    __syncthreads();
  }

  float4 bv = make_float4(0.f, 0.f, 0.f, 0.f);
  if (bias) bv = *(const float4*)(bias + bn + tn);
#pragma unroll
  for (int i = 0; i < 4; ++i) {
    int row = bm + tm + i;
    if (row < M) {
      float4 o;
      o.x = acc[i][0] + bv.x;
      o.y = acc[i][1] + bv.y;
      o.z = acc[i][2] + bv.z;
      o.w = acc[i][3] + bv.w;
      *(float4*)(C + (long)row * ldc + bn + tn) = o;
    }
  }
}

// ------------------------------------------------------- CSR mean-aggregate
// One wave per node; lane owns 2 dims. OUT[d] += sum_e winv[d,t] * T[src_e, t-r0]
__global__ __launch_bounds__(256) void aggregate(
    const int* __restrict__ eids, const int* __restrict__ rowstart,
    const int* __restrict__ src, const int* __restrict__ et,
    const float* __restrict__ winv, const float* __restrict__ T,
    float* __restrict__ OUT, int r0, int G) {
  int node = blockIdx.x * 4 + (threadIdx.x >> 6);
  if (node >= NN) return;
  int lane = threadIdx.x & 63;
  int e0 = rowstart[node], e1 = rowstart[node + 1];
  int TW = G * HID;
  float2 acc = make_float2(0.f, 0.f);
  for (int p = e0; p < e1; ++p) {
    int e = eids[p];
    int t = et[e];
    if ((unsigned)(t - r0) < (unsigned)G) {
      int s = src[e];
      float w = winv[node * NREL + t];
      float2 v = *(const float2*)(T + (long)s * TW + (t - r0) * HID + lane * 2);
      acc.x += w * v.x;
      acc.y += w * v.y;
    }
  }
  float2* o = (float2*)(OUT + (long)node * HID + lane * 2);
  float2 cur = *o;
  cur.x += acc.x;
  cur.y += acc.y;
  *o = cur;
}

// --------------------------------------------------- LN + ReLU + residual
__global__ __launch_bounds__(256) void ln_relu_res(
    const float* __restrict__ OUT, const float* __restrict__ res,
    const float* __restrict__ g, const float* __restrict__ b,
    float* __restrict__ hn) {
  int node = blockIdx.x * 4 + (threadIdx.x >> 6);
  if (node >= NN) return;
  int lane = threadIdx.x & 63;
  float2 v = *(const float2*)(OUT + (long)node * HID + lane * 2);
  float s = v.x + v.y;
  float sq = v.x * v.x + v.y * v.y;
#pragma unroll
  for (int off = 32; off; off >>= 1) {
    s += __shfl_xor(s, off);
    sq += __shfl_xor(sq, off);
  }
  float mu = s * (1.f / HID);
  float var = sq * (1.f / HID) - mu * mu;
  float rs = rsqrtf(var + LN_EPS);
  float2 gg = *(const float2*)(g + lane * 2);
  float2 bb = *(const float2*)(b + lane * 2);
  float2 rr = *(const float2*)(res + (long)node * HID + lane * 2);
  float y0 = fmaxf((v.x - mu) * rs * gg.x + bb.x, 0.f) + rr.x;
  float y1 = fmaxf((v.y - mu) * rs * gg.y + bb.y, 0.f) + rr.y;
  *(float2*)(hn + (long)node * HID + lane * 2) = make_float2(y0, y1);
}

// ---------------------------------------------------------------- pooling
__global__ void pool_kernel(const float* __restrict__ h, const int* __restrict__ batch,
                            float* __restrict__ out) {
  int n0 = blockIdx.x * 64;
  if (n0 >= NN) return;
  int t = threadIdx.x;  // 128 threads = dims
  int nend = min(n0 + 64, NN);
  int cur = batch[n0];
  float acc = 0.f;
  for (int n = n0; n < nend; ++n) {
    int gph = batch[n];
    if (gph != cur) {
      atomicAdd(&out[cur * HID + t], acc);
      acc = 0.f;
      cur = gph;
    }
    acc += h[(long)n * HID + t];
  }
  atomicAdd(&out[cur * HID + t], acc);
}

// ---------------------------------------------------------------- launch
extern "C" void kernel_launch(void* const* d_in, const int* in_sizes, int n_in,
                              void* d_out, int out_size, void* d_ws, size_t ws_size,
                              hipStream_t stream) {
  const float* x = (const float*)d_in[0];
  const int* ei = (const int*)d_in[1];
  const int* et = (const int*)d_in[2];
  const int* batch = (const int*)d_in[3];
  const float* Wp = (const float*)d_in[4];
  const float* bp = (const float*)d_in[5];
  const float* rel_w = (const float*)d_in[6];
  const float* root_w = (const float*)d_in[7];
  const float* conv_b = (const float*)d_in[8];
  const float* ln_g = (const float*)d_in[9];
  const float* ln_b = (const float*)d_in[10];
  float* out = (float*)d_out;
  const int* srcv = ei;
  const int* dstv = ei + NE;

  char* w = (char*)d_ws;
  auto alloc = [&](size_t bytes) {
    char* p = w;
    w += (bytes + 255) & ~(size_t)255;
    return p;
  };
  float* h0 = (float*)alloc((size_t)NN * HID * 4);
  float* h1 = (float*)alloc((size_t)NN * HID * 4);
  float* OUT = (float*)alloc((size_t)NN * HID * 4);
  float* winv = (float*)alloc((size_t)NN * NREL * 4);
  int* deg = (int*)alloc((size_t)NN * 4);
  int* rowstart = (int*)alloc((size_t)(NN + 1) * 4);
  int* fillpos = (int*)alloc((size_t)NN * 4);
  int* eids = (int*)alloc((size_t)NE * 4);
  int* partial = (int*)alloc(256 * 4);
  size_t used = (size_t)(w - (char*)d_ws);
  size_t rem = (ws_size > used) ? ws_size - used : 0;
  int G = 1;
  if (rem >= (size_t)NN * 10 * HID * 4) G = 10;
  else if (rem >= (size_t)NN * 5 * HID * 4) G = 5;
  else if (rem >= (size_t)NN * 2 * HID * 4) G = 2;
  float* T = (float*)alloc((size_t)NN * G * HID * 4);
  const int P = NREL / G;

  const int NB_E = (NE + 255) / 256;
  const int NB_N = (NN + 255) / 256;  // 196

  // zero what we accumulate into
  zero_kernel<<<dim3(512), dim3(256), 0, stream>>>(winv, NN * NREL);
  zero_kernel<<<dim3(256), dim3(256), 0, stream>>>((float*)deg, NN);
  zero_kernel<<<dim3(256), dim3(256), 0, stream>>>((float*)fillpos, NN);
  zero_kernel<<<dim3(32), dim3(256), 0, stream>>>(out, NG * HID);

  // counts -> winv ; CSR build
  count_edges<<<dim3(NB_E), dim3(256), 0, stream>>>(dstv, et, winv, deg);
  invert_winv<<<dim3((NN * NREL + 255) / 256), dim3(256), 0, stream>>>(winv);
  scan_block<<<dim3(NB_N), dim3(256), 0, stream>>>(deg, rowstart, partial);
  scan_partials<<<dim3(1), dim3(256), 0, stream>>>(partial, NB_N);
  scan_add<<<dim3(NB_N), dim3(256), 0, stream>>>(rowstart, partial);
  fill_eids<<<dim3(NB_E), dim3(256), 0, stream>>>(dstv, fillpos, rowstart, eids);

  const int MB = (NN + BM - 1) / BM;  // 782

  // projection: h0 = x @ Wp + bp
  gemm_f32<<<dim3(HID / BN, MB), dim3(256), 0, stream>>>(
      x, Wp, bp, h0, NN, IND, HID, (long)HID * HID, HID);

  float* hc = h0;
  float* hn = h1;
  for (int l = 0; l < NLAY; ++l) {
    // OUT = hc @ root_w[l] + conv_b[l]
    gemm_f32<<<dim3(HID / BN, MB), dim3(256), 0, stream>>>(
        hc, root_w + (size_t)l * HID * HID, conv_b + (size_t)l * HID, OUT,
        NN, HID, HID, (long)HID * HID, HID);
    for (int p = 0; p < P; ++p) {
      // T = hc @ rel_w[l][pG .. pG+G)
      gemm_f32<<<dim3(G * HID / BN, MB), dim3(256), 0, stream>>>(
          hc, rel_w + ((size_t)l * NREL + (size_t)p * G) * HID * HID, nullptr, T,
          NN, HID, HID, (long)HID * HID, G * HID);
      aggregate<<<dim3(NN / 4), dim3(256), 0, stream>>>(
          eids, rowstart, srcv, et, winv, T, OUT, p * G, G);
    }
    ln_relu_res<<<dim3(NN / 4), dim3(256), 0, stream>>>(
        OUT, hc, ln_g + (size_t)l * HID, ln_b + (size_t)l * HID, hn);
    float* tmp = hc; hc = hn; hn = tmp;
  }

  pool_kernel<<<dim3((NN + 63) / 64), dim3(128), 0, stream>>>(hc, batch, out);
}

// Round 2
// 2653.763 us; speedup vs baseline: 1.1134x; 1.1134x over previous
//
#include <hip/hip_runtime.h>

#define NN 50000
#define NE 600000
#define IND 64
#define HID 128
#define NREL 10
#define NLAY 6
#define NG 64
#define LN_EPS 1e-5f

typedef __attribute__((ext_vector_type(8))) short bf8;
typedef __attribute__((ext_vector_type(4))) float f4;

__device__ __forceinline__ ushort f2bf(float x) {
  uint u = __float_as_uint(x);
  u += 0x7fff + ((u >> 16) & 1);
  return (ushort)(u >> 16);
}
__device__ __forceinline__ float bf2f(ushort h) {
  return __uint_as_float(((uint)h) << 16);
}

// ---------------------------------------------------------------- utilities
__global__ void zero_kernel(float* __restrict__ p, int n) {
  int i = blockIdx.x * blockDim.x + threadIdx.x;
  int stride = gridDim.x * blockDim.x;
  for (; i < n; i += stride) p[i] = 0.f;
}

__global__ void count_edges(const int* __restrict__ dst, const int* __restrict__ et,
                            float* __restrict__ winv, int* __restrict__ deg) {
  int e = blockIdx.x * 256 + threadIdx.x;
  if (e >= NE) return;
  int d = dst[e];
  atomicAdd(&winv[d * NREL + et[e]], 1.0f);
  atomicAdd(&deg[d], 1);
}

__global__ void invert_winv(float* __restrict__ winv) {
  int i = blockIdx.x * 256 + threadIdx.x;
  if (i < NN * NREL) winv[i] = 1.0f / fmaxf(winv[i], 1.0f);
}

__global__ void scan_block(const int* __restrict__ deg, int* __restrict__ rowstart,
                           int* __restrict__ partial) {
  __shared__ int sh[256];
  int i = blockIdx.x * 256 + threadIdx.x;
  int v = (i < NN) ? deg[i] : 0;
  sh[threadIdx.x] = v;
  __syncthreads();
  int x = v;
  for (int off = 1; off < 256; off <<= 1) {
    int y = (threadIdx.x >= off) ? sh[threadIdx.x - off] : 0;
    __syncthreads();
    x += y;
    sh[threadIdx.x] = x;
    __syncthreads();
  }
  if (i < NN) rowstart[i] = x - v;
  if (threadIdx.x == 255) partial[blockIdx.x] = x;
}

__global__ void scan_partials(int* __restrict__ partial, int nb) {
  __shared__ int sh[256];
  int v = (threadIdx.x < nb) ? partial[threadIdx.x] : 0;
  sh[threadIdx.x] = v;
  __syncthreads();
  int x = v;
  for (int off = 1; off < 256; off <<= 1) {
    int y = (threadIdx.x >= off) ? sh[threadIdx.x - off] : 0;
    __syncthreads();
    x += y;
    sh[threadIdx.x] = x;
    __syncthreads();
  }
  partial[threadIdx.x] = x - v;
}

__global__ void scan_add(int* __restrict__ rowstart, const int* __restrict__ partial) {
  int i = blockIdx.x * 256 + threadIdx.x;
  if (i < NN) rowstart[i] += partial[i >> 8];
  if (i == 0) rowstart[NN] = NE;
}

__global__ void fill_eids(const int* __restrict__ dst, int* __restrict__ fillpos,
                          const int* __restrict__ rowstart, int* __restrict__ eids) {
  int e = blockIdx.x * 256 + threadIdx.x;
  if (e >= NE) return;
  int d = dst[e];
  int pos = rowstart[d] + atomicAdd(&fillpos[d], 1);
  eids[pos] = e;
}

// ------------------------------------------------------------- weight prep
// src: nmat matrices [K][128] fp32 -> dh/dl: [nmat][128][K] bf16 (transposed)
__global__ void transpose_split(const float* __restrict__ src, ushort* __restrict__ dh,
                                ushort* __restrict__ dl, int nmat, int K) {
  int i = blockIdx.x * 256 + threadIdx.x;
  int tot = nmat * K * HID;
  if (i >= tot) return;
  int m = i / (K * HID);
  int rem = i - m * (K * HID);
  int k = rem / HID;
  int n = rem - k * HID;
  float v = src[i];
  ushort h = f2bf(v);
  ushort l = f2bf(v - bf2f(h));
  int o = m * K * HID + n * K + k;
  dh[o] = h;
  dl[o] = l;
}

// flat fp32 -> bf16 hi/lo (linear layout)
__global__ void split_rows(const float* __restrict__ s, ushort* __restrict__ dh,
                           ushort* __restrict__ dl, int n) {
  int i = blockIdx.x * 256 + threadIdx.x;
  if (i >= n) return;
  float v = s[i];
  ushort h = f2bf(v);
  dh[i] = h;
  dl[i] = f2bf(v - bf2f(h));
}

// ----------------------------------------------------- bf16x3 MFMA GEMM
// C[M x (nblk*128)] = A[M x K] @ B, fp32-equivalent precision via 3-term split.
// A: hi/lo bf16 [M][K] linear. B: hi/lo bf16 [nblk][128][K] (transposed).
// Block: 256 thr (4 waves, 2x2), BM=128, BN=128, whole K staged in LDS with
// XOR swizzle (byte ^= (row&7)<<4) to kill stride-256B bank conflicts.
template <int K>
__global__ __launch_bounds__(256) void gemm3(
    const ushort* __restrict__ Ah, const ushort* __restrict__ Al,
    const ushort* __restrict__ Bh, const ushort* __restrict__ Bl,
    const float* __restrict__ bias, float* __restrict__ Cf,
    ushort* __restrict__ Cb, int M, int ldc) {
  constexpr int RB = K * 2;  // row bytes
  __shared__ __align__(16) char lds[4 * 128 * RB];
  char* As_h = lds;
  char* As_l = lds + 128 * RB;
  char* Bs_h = lds + 2 * 128 * RB;
  char* Bs_l = lds + 3 * 128 * RB;

  const int tid = threadIdx.x;
  const int bm = blockIdx.y * 128;
  const ushort* Bhm = Bh + (size_t)blockIdx.x * 128 * K;
  const ushort* Blm = Bl + (size_t)blockIdx.x * 128 * K;

  constexpr int UNITS = 128 * RB / 16;
  for (int u = tid; u < UNITS; u += 256) {
    int row = (u * 16) / RB;
    int off = (u * 16) % RB;
    int soff = off ^ ((row & 7) << 4);
    int grow = bm + row;
    bf8 va = {}, vb = {};
    if (grow < M) {
      va = *(const bf8*)((const char*)Ah + ((size_t)grow * RB + off));
      vb = *(const bf8*)((const char*)Al + ((size_t)grow * RB + off));
    }
    *(bf8*)(As_h + row * RB + soff) = va;
    *(bf8*)(As_l + row * RB + soff) = vb;
    bf8 wh = *(const bf8*)((const char*)Bhm + ((size_t)row * RB + off));
    bf8 wl = *(const bf8*)((const char*)Blm + ((size_t)row * RB + off));
    *(bf8*)(Bs_h + row * RB + soff) = wh;
    *(bf8*)(Bs_l + row * RB + soff) = wl;
  }
  __syncthreads();

  const int w = tid >> 6, lane = tid & 63;
  const int wr = (w >> 1) * 64, wc = (w & 1) * 64;
  const int lr = lane & 15;
  const int kb = (lane >> 4) * 16;  // byte offset of this lane's 8 bf16 in a 64B k-chunk

  f4 acc[4][4] = {};

#pragma unroll
  for (int ks = 0; ks < K / 32; ++ks) {
    bf8 ah[4], al[4], bh[4], bl[4];
#pragma unroll
    for (int m = 0; m < 4; ++m) {
      int row = wr + m * 16 + lr;
      int off = (ks * 64 + kb) ^ ((row & 7) << 4);
      ah[m] = *(const bf8*)(As_h + row * RB + off);
      al[m] = *(const bf8*)(As_l + row * RB + off);
    }
#pragma unroll
    for (int n = 0; n < 4; ++n) {
      int row = wc + n * 16 + lr;
      int off = (ks * 64 + kb) ^ ((row & 7) << 4);
      bh[n] = *(const bf8*)(Bs_h + row * RB + off);
      bl[n] = *(const bf8*)(Bs_l + row * RB + off);
    }
#pragma unroll
    for (int m = 0; m < 4; ++m)
#pragma unroll
      for (int n = 0; n < 4; ++n) {
        acc[m][n] = __builtin_amdgcn_mfma_f32_16x16x32_bf16(ah[m], bh[n], acc[m][n], 0, 0, 0);
        acc[m][n] = __builtin_amdgcn_mfma_f32_16x16x32_bf16(al[m], bh[n], acc[m][n], 0, 0, 0);
        acc[m][n] = __builtin_amdgcn_mfma_f32_16x16x32_bf16(ah[m], bl[n], acc[m][n], 0, 0, 0);
      }
  }

  const int rgrp = (lane >> 4) * 4;
#pragma unroll
  for (int n = 0; n < 4; ++n) {
    int colin = wc + n * 16 + lr;                 // col within 128-block
    int col = blockIdx.x * 128 + colin;           // col in C
    float bv = bias ? bias[colin] : 0.f;
#pragma unroll
    for (int m = 0; m < 4; ++m) {
      int r0 = bm + wr + m * 16 + rgrp;
#pragma unroll
      for (int j = 0; j < 4; ++j) {
        int r = r0 + j;
        if (r < M) {
          float v = acc[m][n][j] + bv;
          if (Cf) Cf[(size_t)r * ldc + col] = v;
          else Cb[(size_t)r * ldc + col] = f2bf(v);
        }
      }
    }
  }
}

// ------------------------------------------------------- CSR mean-aggregate
// One wave per node; lane owns 2 dims. OUT[d] += sum_e winv[d,t] * T[src_e, t-r0]
__global__ __launch_bounds__(256) void aggregate(
    const int* __restrict__ eids, const int* __restrict__ rowstart,
    const int* __restrict__ src, const int* __restrict__ et,
    const float* __restrict__ winv, const ushort* __restrict__ T,
    float* __restrict__ OUT, int r0, int G) {
  int node = blockIdx.x * 4 + (threadIdx.x >> 6);
  if (node >= NN) return;
  int lane = threadIdx.x & 63;
  int e0 = rowstart[node], e1 = rowstart[node + 1];
  int TW = G * HID;
  float ax = 0.f, ay = 0.f;
  for (int p = e0; p < e1; ++p) {
    int e = eids[p];
    int t = et[e];
    if ((unsigned)(t - r0) < (unsigned)G) {
      int s = src[e];
      float wgt = winv[node * NREL + t];
      uint v = *(const uint*)(T + (size_t)s * TW + (t - r0) * HID + lane * 2);
      ax += wgt * bf2f((ushort)(v & 0xffffu));
      ay += wgt * bf2f((ushort)(v >> 16));
    }
  }
  float2* o = (float2*)(OUT + (size_t)node * HID + lane * 2);
  float2 cur = *o;
  cur.x += ax;
  cur.y += ay;
  *o = cur;
}

// ------------------------------------- LN + ReLU + residual (+ bf16 split)
__global__ __launch_bounds__(256) void ln_relu_res(
    const float* __restrict__ OUT, float* __restrict__ h,  // h: residual in, new h out
    const float* __restrict__ g, const float* __restrict__ b,
    ushort* __restrict__ dh, ushort* __restrict__ dl) {
  int node = blockIdx.x * 4 + (threadIdx.x >> 6);
  if (node >= NN) return;
  int lane = threadIdx.x & 63;
  float2 v = *(const float2*)(OUT + (size_t)node * HID + lane * 2);
  float s = v.x + v.y;
  float sq = v.x * v.x + v.y * v.y;
#pragma unroll
  for (int off = 32; off; off >>= 1) {
    s += __shfl_xor(s, off);
    sq += __shfl_xor(sq, off);
  }
  float mu = s * (1.f / HID);
  float var = sq * (1.f / HID) - mu * mu;
  float rs = rsqrtf(var + LN_EPS);
  float2 gg = *(const float2*)(g + lane * 2);
  float2 bb = *(const float2*)(b + lane * 2);
  float2 rr = *(const float2*)(h + (size_t)node * HID + lane * 2);
  float y0 = fmaxf((v.x - mu) * rs * gg.x + bb.x, 0.f) + rr.x;
  float y1 = fmaxf((v.y - mu) * rs * gg.y + bb.y, 0.f) + rr.y;
  *(float2*)(h + (size_t)node * HID + lane * 2) = make_float2(y0, y1);
  ushort h0 = f2bf(y0), h1 = f2bf(y1);
  ushort l0 = f2bf(y0 - bf2f(h0)), l1 = f2bf(y1 - bf2f(h1));
  *(uint*)(dh + (size_t)node * HID + lane * 2) = (uint)h0 | ((uint)h1 << 16);
  *(uint*)(dl + (size_t)node * HID + lane * 2) = (uint)l0 | ((uint)l1 << 16);
}

// ---------------------------------------------------------------- pooling
__global__ void pool_kernel(const float* __restrict__ h, const int* __restrict__ batch,
                            float* __restrict__ out) {
  int n0 = blockIdx.x * 64;
  if (n0 >= NN) return;
  int t = threadIdx.x;  // 128 threads = dims
  int nend = min(n0 + 64, NN);
  int cur = batch[n0];
  float acc = 0.f;
  for (int n = n0; n < nend; ++n) {
    int gph = batch[n];
    if (gph != cur) {
      atomicAdd(&out[cur * HID + t], acc);
      acc = 0.f;
      cur = gph;
    }
    acc += h[(size_t)n * HID + t];
  }
  atomicAdd(&out[cur * HID + t], acc);
}

// ---------------------------------------------------------------- launch
extern "C" void kernel_launch(void* const* d_in, const int* in_sizes, int n_in,
                              void* d_out, int out_size, void* d_ws, size_t ws_size,
                              hipStream_t stream) {
  const float* x = (const float*)d_in[0];
  const int* ei = (const int*)d_in[1];
  const int* et = (const int*)d_in[2];
  const int* batch = (const int*)d_in[3];
  const float* Wp = (const float*)d_in[4];
  const float* bp = (const float*)d_in[5];
  const float* rel_w = (const float*)d_in[6];
  const float* root_w = (const float*)d_in[7];
  const float* conv_b = (const float*)d_in[8];
  const float* ln_g = (const float*)d_in[9];
  const float* ln_b = (const float*)d_in[10];
  float* out = (float*)d_out;
  const int* srcv = ei;
  const int* dstv = ei + NE;

  char* w = (char*)d_ws;
  auto alloc = [&](size_t bytes) {
    char* p = w;
    w += (bytes + 255) & ~(size_t)255;
    return p;
  };
  float* h = (float*)alloc((size_t)NN * HID * 4);
  float* OUT = (float*)alloc((size_t)NN * HID * 4);
  float* winv = (float*)alloc((size_t)NN * NREL * 4);
  int* deg = (int*)alloc((size_t)NN * 4);
  int* rowstart = (int*)alloc((size_t)(NN + 1) * 4);
  int* fillpos = (int*)alloc((size_t)NN * 4);
  int* eids = (int*)alloc((size_t)NE * 4);
  int* partial = (int*)alloc(256 * 4);
  ushort* hh = (ushort*)alloc((size_t)NN * HID * 2);  // also aliased as x_hi [NN][64]
  ushort* hl = (ushort*)alloc((size_t)NN * HID * 2);  // also aliased as x_lo
  ushort* Wph = (ushort*)alloc((size_t)IND * HID * 2);
  ushort* Wpl = (ushort*)alloc((size_t)IND * HID * 2);
  ushort* Rth = (ushort*)alloc((size_t)NLAY * HID * HID * 2);
  ushort* Rtl = (ushort*)alloc((size_t)NLAY * HID * HID * 2);
  ushort* Relh = (ushort*)alloc((size_t)NLAY * NREL * HID * HID * 2);
  ushort* Rell = (ushort*)alloc((size_t)NLAY * NREL * HID * HID * 2);

  size_t used = (size_t)(w - (char*)d_ws);
  size_t rem = (ws_size > used) ? ws_size - used : 0;
  int G = 1;
  if (rem >= (size_t)NN * 10 * HID * 2) G = 10;
  else if (rem >= (size_t)NN * 5 * HID * 2) G = 5;
  else if (rem >= (size_t)NN * 2 * HID * 2) G = 2;
  ushort* T = (ushort*)alloc((size_t)NN * G * HID * 2);
  const int P = NREL / G;

  const int NB_E = (NE + 255) / 256;
  const int NB_N = (NN + 255) / 256;
  const int MB = (NN + 127) / 128;  // 391

  zero_kernel<<<dim3(512), dim3(256), 0, stream>>>(winv, NN * NREL);
  zero_kernel<<<dim3(256), dim3(256), 0, stream>>>((float*)deg, NN);
  zero_kernel<<<dim3(256), dim3(256), 0, stream>>>((float*)fillpos, NN);
  zero_kernel<<<dim3(32), dim3(256), 0, stream>>>(out, NG * HID);

  count_edges<<<dim3(NB_E), dim3(256), 0, stream>>>(dstv, et, winv, deg);
  invert_winv<<<dim3((NN * NREL + 255) / 256), dim3(256), 0, stream>>>(winv);
  scan_block<<<dim3(NB_N), dim3(256), 0, stream>>>(deg, rowstart, partial);
  scan_partials<<<dim3(1), dim3(256), 0, stream>>>(partial, NB_N);
  scan_add<<<dim3(NB_N), dim3(256), 0, stream>>>(rowstart, partial);
  fill_eids<<<dim3(NB_E), dim3(256), 0, stream>>>(dstv, fillpos, rowstart, eids);

  // weight transpose+split (once per call; tiny)
  transpose_split<<<dim3((IND * HID + 255) / 256), dim3(256), 0, stream>>>(Wp, Wph, Wpl, 1, IND);
  transpose_split<<<dim3((NLAY * HID * HID + 255) / 256), dim3(256), 0, stream>>>(
      root_w, Rth, Rtl, NLAY, HID);
  transpose_split<<<dim3((NLAY * NREL * HID * HID + 255) / 256), dim3(256), 0, stream>>>(
      rel_w, Relh, Rell, NLAY * NREL, HID);

  // x split (aliases hh/hl as [NN][64])
  split_rows<<<dim3((NN * IND + 255) / 256), dim3(256), 0, stream>>>(x, hh, hl, NN * IND);

  // projection: h = x @ Wp + bp
  gemm3<IND><<<dim3(1, MB), dim3(256), 0, stream>>>(hh, hl, Wph, Wpl, bp, h, (ushort*)nullptr,
                                                    NN, HID);
  split_rows<<<dim3((NN * HID + 255) / 256), dim3(256), 0, stream>>>(h, hh, hl, NN * HID);

  for (int l = 0; l < NLAY; ++l) {
    gemm3<HID><<<dim3(1, MB), dim3(256), 0, stream>>>(
        hh, hl, Rth + (size_t)l * HID * HID, Rtl + (size_t)l * HID * HID,
        conv_b + (size_t)l * HID, OUT, (ushort*)nullptr, NN, HID);
    for (int p = 0; p < P; ++p) {
      gemm3<HID><<<dim3(G, MB), dim3(256), 0, stream>>>(
          hh, hl, Relh + ((size_t)l * NREL + (size_t)p * G) * HID * HID,
          Rell + ((size_t)l * NREL + (size_t)p * G) * HID * HID,
          (const float*)nullptr, (float*)nullptr, T, NN, G * HID);
      aggregate<<<dim3(NN / 4), dim3(256), 0, stream>>>(
          eids, rowstart, srcv, et, winv, T, OUT, p * G, G);
    }
    ln_relu_res<<<dim3(NN / 4), dim3(256), 0, stream>>>(
        OUT, h, ln_g + (size_t)l * HID, ln_b + (size_t)l * HID, hh, hl);
  }

  pool_kernel<<<dim3((NN + 63) / 64), dim3(128), 0, stream>>>(h, batch, out);
}

// Round 3
// 1627.758 us; speedup vs baseline: 1.8151x; 1.6303x over previous
//
#include <hip/hip_runtime.h>

#define NN 50000
#define NE 600000
#define IND 64
#define HID 128
#define NREL 10
#define NLAY 6
#define NG 64
#define LN_EPS 1e-5f

typedef __attribute__((ext_vector_type(8))) short bf8;
typedef __attribute__((ext_vector_type(4))) float f4;

__device__ __forceinline__ ushort f2bf(float x) {
  uint u = __float_as_uint(x);
  u += 0x7fff + ((u >> 16) & 1);
  return (ushort)(u >> 16);
}
__device__ __forceinline__ float bf2f(ushort h) {
  return __uint_as_float(((uint)h) << 16);
}

// ---------------------------------------------------------------- utilities
__global__ void zero_kernel(float* __restrict__ p, int n) {
  int i = blockIdx.x * blockDim.x + threadIdx.x;
  int stride = gridDim.x * blockDim.x;
  for (; i < n; i += stride) p[i] = 0.f;
}

__global__ void count_edges(const int* __restrict__ dst, const int* __restrict__ et,
                            float* __restrict__ winv, int* __restrict__ deg) {
  int e = blockIdx.x * 256 + threadIdx.x;
  if (e >= NE) return;
  int d = dst[e];
  atomicAdd(&winv[d * NREL + et[e]], 1.0f);
  atomicAdd(&deg[d], 1);
}

__global__ void invert_winv(float* __restrict__ winv) {
  int i = blockIdx.x * 256 + threadIdx.x;
  if (i < NN * NREL) winv[i] = 1.0f / fmaxf(winv[i], 1.0f);
}

__global__ void scan_block(const int* __restrict__ deg, int* __restrict__ rowstart,
                           int* __restrict__ partial) {
  __shared__ int sh[256];
  int i = blockIdx.x * 256 + threadIdx.x;
  int v = (i < NN) ? deg[i] : 0;
  sh[threadIdx.x] = v;
  __syncthreads();
  int x = v;
  for (int off = 1; off < 256; off <<= 1) {
    int y = (threadIdx.x >= off) ? sh[threadIdx.x - off] : 0;
    __syncthreads();
    x += y;
    sh[threadIdx.x] = x;
    __syncthreads();
  }
  if (i < NN) rowstart[i] = x - v;
  if (threadIdx.x == 255) partial[blockIdx.x] = x;
}

__global__ void scan_partials(int* __restrict__ partial, int nb) {
  __shared__ int sh[256];
  int v = (threadIdx.x < nb) ? partial[threadIdx.x] : 0;
  sh[threadIdx.x] = v;
  __syncthreads();
  int x = v;
  for (int off = 1; off < 256; off <<= 1) {
    int y = (threadIdx.x >= off) ? sh[threadIdx.x - off] : 0;
    __syncthreads();
    x += y;
    sh[threadIdx.x] = x;
    __syncthreads();
  }
  partial[threadIdx.x] = x - v;
}

__global__ void scan_add(int* __restrict__ rowstart, const int* __restrict__ partial) {
  int i = blockIdx.x * 256 + threadIdx.x;
  if (i < NN) rowstart[i] += partial[i >> 8];
  if (i == 0) rowstart[NN] = NE;
}

__global__ void fill_eids(const int* __restrict__ dst, int* __restrict__ fillpos,
                          const int* __restrict__ rowstart, int* __restrict__ eids) {
  int e = blockIdx.x * 256 + threadIdx.x;
  if (e >= NE) return;
  int d = dst[e];
  int pos = rowstart[d] + atomicAdd(&fillpos[d], 1);
  eids[pos] = e;
}

// ------------------------------------------------------------- weight prep
// src: nmat [K][128] fp32 -> fragment-linear bf16 hi/lo:
// elem (m, k, n) -> m*K*128 + (n>>4)*(K*16) + (k>>3)*128 + (n&15)*8 + (k&7)
__global__ void transpose_split_frag(const float* __restrict__ src, ushort* __restrict__ dh,
                                     ushort* __restrict__ dl, int nmat, int K) {
  int i = blockIdx.x * 256 + threadIdx.x;
  int tot = nmat * K * 128;
  if (i >= tot) return;
  int m = i / (K * 128);
  int rem = i - m * (K * 128);
  int k = rem / 128;
  int n = rem - k * 128;
  float v = src[i];
  ushort h = f2bf(v);
  size_t o = (size_t)m * (K * 128) + (size_t)(n >> 4) * (K * 16) + (k >> 3) * 128 +
             (n & 15) * 8 + (k & 7);
  dh[o] = h;
  dl[o] = f2bf(v - bf2f(h));
}

// rows fp32 [N][K] -> fragment-linear bf16 hi/lo, one 16-row group per block
template <int K>
__global__ __launch_bounds__(256) void split_frag(const float* __restrict__ src,
                                                  ushort* __restrict__ dh,
                                                  ushort* __restrict__ dl) {
  constexpr int TOT = 16 * K;
  __shared__ ushort sh[TOT], sl[TOT];
  int grp = blockIdx.x;
  const float* s = src + (size_t)grp * TOT;
  for (int i = threadIdx.x * 4; i < TOT; i += 1024) {
    float4 v = *(const float4*)(s + i);
    int nl = i / K, d = i - nl * K;
    int off = (d >> 3) * 128 + nl * 8 + (d & 7);
    ushort h0 = f2bf(v.x), h1 = f2bf(v.y), h2 = f2bf(v.z), h3 = f2bf(v.w);
    *(uint*)(sh + off) = (uint)h0 | ((uint)h1 << 16);
    *(uint*)(sh + off + 2) = (uint)h2 | ((uint)h3 << 16);
    *(uint*)(sl + off) = (uint)f2bf(v.x - bf2f(h0)) | ((uint)f2bf(v.y - bf2f(h1)) << 16);
    *(uint*)(sl + off + 2) = (uint)f2bf(v.z - bf2f(h2)) | ((uint)f2bf(v.w - bf2f(h3)) << 16);
  }
  __syncthreads();
  size_t base = (size_t)grp * TOT;
  for (int i = threadIdx.x * 8; i < TOT; i += 2048) {
    *(bf8*)(dh + base + i) = *(const bf8*)(sh + i);
    *(bf8*)(dl + base + i) = *(const bf8*)(sl + i);
  }
}

// ----------------------------------------------------- LDS-free bf16x3 GEMM
struct Frags {
  bf8 ah[4], al[4], bh[4], bl[4];
};

template <int K>
__device__ __forceinline__ void load_frags(Frags& f, int ks, const ushort* Abh,
                                           const ushort* Abl, const ushort* Bbh,
                                           const ushort* Bbl) {
#pragma unroll
  for (int m = 0; m < 4; ++m) {
    f.ah[m] = *(const bf8*)(Abh + (size_t)m * (K * 16) + ks * 512);
    f.al[m] = *(const bf8*)(Abl + (size_t)m * (K * 16) + ks * 512);
  }
#pragma unroll
  for (int n = 0; n < 4; ++n) {
    f.bh[n] = *(const bf8*)(Bbh + (size_t)n * (K * 16) + ks * 512);
    f.bl[n] = *(const bf8*)(Bbl + (size_t)n * (K * 16) + ks * 512);
  }
}

__device__ __forceinline__ void mfma_frags(f4 (&acc)[4][4], const Frags& f) {
#pragma unroll
  for (int m = 0; m < 4; ++m)
#pragma unroll
    for (int n = 0; n < 4; ++n) {
      acc[m][n] = __builtin_amdgcn_mfma_f32_16x16x32_bf16(f.ah[m], f.bh[n], acc[m][n], 0, 0, 0);
      acc[m][n] = __builtin_amdgcn_mfma_f32_16x16x32_bf16(f.al[m], f.bh[n], acc[m][n], 0, 0, 0);
      acc[m][n] = __builtin_amdgcn_mfma_f32_16x16x32_bf16(f.ah[m], f.bl[n], acc[m][n], 0, 0, 0);
    }
}

// C[M x (nx*128)] = A @ B (3-term bf16 split, fp32-equiv). No LDS, no barriers.
// A,B in fragment-linear layout. Cf: fp32 [M][128] (+bias). Cb: bf16 [M][ldc].
template <int K>
__global__ __launch_bounds__(256) void gemm_frag(
    const ushort* __restrict__ Ah, const ushort* __restrict__ Al,
    const ushort* __restrict__ Bh, const ushort* __restrict__ Bl,
    const float* __restrict__ bias, float* __restrict__ Cf, ushort* __restrict__ Cb,
    int ldc, int M) {
  // XCD-bijective swizzle, x-fastest: the nx blocks sharing an A-panel land on one XCD
  int nwg = gridDim.x * gridDim.y;
  int lin = blockIdx.y * gridDim.x + blockIdx.x;
  int q = nwg >> 3, r8 = nwg & 7;
  int xcd = lin & 7, sub = lin >> 3;
  int swz = (xcd < r8) ? (xcd * (q + 1) + sub) : (r8 * (q + 1) + (xcd - r8) * q + sub);
  int bx = swz % gridDim.x;
  int by = swz / gridDim.x;

  const int bm = by * 128;
  const int tid = threadIdx.x, w = tid >> 6, lane = tid & 63;
  const int wr = (w >> 1) * 64, wc = (w & 1) * 64;
  const int lr = lane & 15;

  const ushort* Abh = Ah + ((size_t)(bm >> 4) + (wr >> 4)) * (K * 16) + lane * 8;
  const ushort* Abl = Al + ((size_t)(bm >> 4) + (wr >> 4)) * (K * 16) + lane * 8;
  const ushort* Bbh = Bh + (size_t)bx * (128 * K) + (size_t)(wc >> 4) * (K * 16) + lane * 8;
  const ushort* Bbl = Bl + (size_t)bx * (128 * K) + (size_t)(wc >> 4) * (K * 16) + lane * 8;

  f4 acc[4][4] = {};
  Frags fa, fb;
  if constexpr (K == 64) {
    load_frags<K>(fa, 0, Abh, Abl, Bbh, Bbl);
    load_frags<K>(fb, 1, Abh, Abl, Bbh, Bbl);
    mfma_frags(acc, fa);
    mfma_frags(acc, fb);
  } else {
    load_frags<K>(fa, 0, Abh, Abl, Bbh, Bbl);
    load_frags<K>(fb, 1, Abh, Abl, Bbh, Bbl);
    mfma_frags(acc, fa);
    load_frags<K>(fa, 2, Abh, Abl, Bbh, Bbl);
    mfma_frags(acc, fb);
    load_frags<K>(fb, 3, Abh, Abl, Bbh, Bbl);
    mfma_frags(acc, fa);
    mfma_frags(acc, fb);
  }

  const int rgrp = (lane >> 4) * 4;
#pragma unroll
  for (int n = 0; n < 4; ++n) {
    int col = wc + n * 16 + lr;
#pragma unroll
    for (int m = 0; m < 4; ++m) {
      int r0 = bm + wr + m * 16 + rgrp;
#pragma unroll
      for (int j = 0; j < 4; ++j) {
        int r = r0 + j;
        if (r < M) {
          float v = acc[m][n][j];
          if (Cf) Cf[(size_t)r * 128 + col] = v + bias[col];
          else Cb[(size_t)r * ldc + bx * 128 + col] = f2bf(v);
        }
      }
    }
  }
}

// ------------------------------------------------------- CSR mean-aggregate
__global__ __launch_bounds__(256) void aggregate(
    const int* __restrict__ eids, const int* __restrict__ rowstart,
    const int* __restrict__ src, const int* __restrict__ et,
    const float* __restrict__ winv, const ushort* __restrict__ T,
    float* __restrict__ OUT, int r0, int G) {
  int node = blockIdx.x * 4 + (threadIdx.x >> 6);
  if (node >= NN) return;
  int lane = threadIdx.x & 63;
  int e0 = rowstart[node], e1 = rowstart[node + 1];
  int TW = G * HID;
  float ax = 0.f, ay = 0.f;
  for (int p = e0; p < e1; ++p) {
    int e = eids[p];
    int t = et[e];
    if ((unsigned)(t - r0) < (unsigned)G) {
      int s = src[e];
      float wgt = winv[node * NREL + t];
      uint v = *(const uint*)(T + (size_t)s * TW + (t - r0) * HID + lane * 2);
      ax += wgt * bf2f((ushort)(v & 0xffffu));
      ay += wgt * bf2f((ushort)(v >> 16));
    }
  }
  float2* o = (float2*)(OUT + (size_t)node * HID + lane * 2);
  float2 cur = *o;
  cur.x += ax;
  cur.y += ay;
  *o = cur;
}

// --------------------- LN + ReLU + residual + fragment-linear bf16 split out
__global__ __launch_bounds__(256) void ln_relu_res_frag(
    const float* __restrict__ OUT, float* __restrict__ h,
    const float* __restrict__ g, const float* __restrict__ b,
    ushort* __restrict__ dh, ushort* __restrict__ dl) {
  __shared__ ushort sh[2048], sl[2048];
  int grp = blockIdx.x;
  int w = threadIdx.x >> 6, lane = threadIdx.x & 63;
  float2 gg = *(const float2*)(g + lane * 2);
  float2 bb = *(const float2*)(b + lane * 2);
#pragma unroll
  for (int p = 0; p < 4; ++p) {
    int r = w * 4 + p;
    int node = grp * 16 + r;
    float2 v = *(const float2*)(OUT + (size_t)node * HID + lane * 2);
    float s = v.x + v.y, sq = v.x * v.x + v.y * v.y;
#pragma unroll
    for (int off = 32; off; off >>= 1) {
      s += __shfl_xor(s, off);
      sq += __shfl_xor(sq, off);
    }
    float mu = s * (1.f / HID);
    float var = sq * (1.f / HID) - mu * mu;
    float rs = rsqrtf(var + LN_EPS);
    float2 rr = *(const float2*)(h + (size_t)node * HID + lane * 2);
    float y0 = fmaxf((v.x - mu) * rs * gg.x + bb.x, 0.f) + rr.x;
    float y1 = fmaxf((v.y - mu) * rs * gg.y + bb.y, 0.f) + rr.y;
    *(float2*)(h + (size_t)node * HID + lane * 2) = make_float2(y0, y1);
    int d = lane * 2;
    int off2 = (d >> 3) * 128 + r * 8 + (d & 7);
    ushort h0 = f2bf(y0), h1 = f2bf(y1);
    *(uint*)(sh + off2) = (uint)h0 | ((uint)h1 << 16);
    *(uint*)(sl + off2) =
        (uint)f2bf(y0 - bf2f(h0)) | ((uint)f2bf(y1 - bf2f(h1)) << 16);
  }
  __syncthreads();
  size_t base = (size_t)grp * 2048;
  int t8 = threadIdx.x * 8;
  *(bf8*)(dh + base + t8) = *(const bf8*)(sh + t8);
  *(bf8*)(dl + base + t8) = *(const bf8*)(sl + t8);
}

// ---------------------------------------------------------------- pooling
__global__ void pool_kernel(const float* __restrict__ h, const int* __restrict__ batch,
                            float* __restrict__ out) {
  int n0 = blockIdx.x * 64;
  if (n0 >= NN) return;
  int t = threadIdx.x;
  int nend = min(n0 + 64, NN);
  int cur = batch[n0];
  float acc = 0.f;
  for (int n = n0; n < nend; ++n) {
    int gph = batch[n];
    if (gph != cur) {
      atomicAdd(&out[cur * HID + t], acc);
      acc = 0.f;
      cur = gph;
    }
    acc += h[(size_t)n * HID + t];
  }
  atomicAdd(&out[cur * HID + t], acc);
}

// ---------------------------------------------------------------- launch
extern "C" void kernel_launch(void* const* d_in, const int* in_sizes, int n_in,
                              void* d_out, int out_size, void* d_ws, size_t ws_size,
                              hipStream_t stream) {
  const float* x = (const float*)d_in[0];
  const int* ei = (const int*)d_in[1];
  const int* et = (const int*)d_in[2];
  const int* batch = (const int*)d_in[3];
  const float* Wp = (const float*)d_in[4];
  const float* bp = (const float*)d_in[5];
  const float* rel_w = (const float*)d_in[6];
  const float* root_w = (const float*)d_in[7];
  const float* conv_b = (const float*)d_in[8];
  const float* ln_g = (const float*)d_in[9];
  const float* ln_b = (const float*)d_in[10];
  float* out = (float*)d_out;
  const int* srcv = ei;
  const int* dstv = ei + NE;

  const int NGRP = NN / 16;        // 3125 (exact)
  const int NGRP_PAD = NGRP + 3;   // GEMM reads up to group 3127

  char* w = (char*)d_ws;
  auto alloc = [&](size_t bytes) {
    char* p = w;
    w += (bytes + 255) & ~(size_t)255;
    return p;
  };
  float* h = (float*)alloc((size_t)NN * HID * 4);
  float* OUT = (float*)alloc((size_t)NN * HID * 4);
  float* winv = (float*)alloc((size_t)NN * NREL * 4);
  int* deg = (int*)alloc((size_t)NN * 4);
  int* rowstart = (int*)alloc((size_t)(NN + 1) * 4);
  int* fillpos = (int*)alloc((size_t)NN * 4);
  int* eids = (int*)alloc((size_t)NE * 4);
  int* partial = (int*)alloc(256 * 4);
  ushort* xh = (ushort*)alloc((size_t)NGRP_PAD * 1024 * 2);
  ushort* xl = (ushort*)alloc((size_t)NGRP_PAD * 1024 * 2);
  ushort* hh = (ushort*)alloc((size_t)NGRP_PAD * 2048 * 2);
  ushort* hl = (ushort*)alloc((size_t)NGRP_PAD * 2048 * 2);
  ushort* Wph = (ushort*)alloc((size_t)IND * HID * 2);
  ushort* Wpl = (ushort*)alloc((size_t)IND * HID * 2);
  ushort* Rth = (ushort*)alloc((size_t)NLAY * HID * HID * 2);
  ushort* Rtl = (ushort*)alloc((size_t)NLAY * HID * HID * 2);
  ushort* Relh = (ushort*)alloc((size_t)NLAY * NREL * HID * HID * 2);
  ushort* Rell = (ushort*)alloc((size_t)NLAY * NREL * HID * HID * 2);

  size_t used = (size_t)(w - (char*)d_ws);
  size_t rem = (ws_size > used) ? ws_size - used : 0;
  int G = 1;
  if (rem >= (size_t)NN * 10 * HID * 2) G = 10;
  else if (rem >= (size_t)NN * 5 * HID * 2) G = 5;
  else if (rem >= (size_t)NN * 2 * HID * 2) G = 2;
  ushort* T = (ushort*)alloc((size_t)NN * G * HID * 2);
  const int P = NREL / G;

  const int NB_E = (NE + 255) / 256;
  const int NB_N = (NN + 255) / 256;
  const int MB = (NN + 127) / 128;  // 391

  zero_kernel<<<dim3(512), dim3(256), 0, stream>>>(winv, NN * NREL);
  zero_kernel<<<dim3(256), dim3(256), 0, stream>>>((float*)deg, NN);
  zero_kernel<<<dim3(256), dim3(256), 0, stream>>>((float*)fillpos, NN);
  zero_kernel<<<dim3(32), dim3(256), 0, stream>>>(out, NG * HID);

  count_edges<<<dim3(NB_E), dim3(256), 0, stream>>>(dstv, et, winv, deg);
  invert_winv<<<dim3((NN * NREL + 255) / 256), dim3(256), 0, stream>>>(winv);
  scan_block<<<dim3(NB_N), dim3(256), 0, stream>>>(deg, rowstart, partial);
  scan_partials<<<dim3(1), dim3(256), 0, stream>>>(partial, NB_N);
  scan_add<<<dim3(NB_N), dim3(256), 0, stream>>>(rowstart, partial);
  fill_eids<<<dim3(NB_E), dim3(256), 0, stream>>>(dstv, fillpos, rowstart, eids);

  transpose_split_frag<<<dim3((IND * HID + 255) / 256), dim3(256), 0, stream>>>(
      Wp, Wph, Wpl, 1, IND);
  transpose_split_frag<<<dim3((NLAY * HID * HID + 255) / 256), dim3(256), 0, stream>>>(
      root_w, Rth, Rtl, NLAY, HID);
  transpose_split_frag<<<dim3((NLAY * NREL * HID * HID + 255) / 256), dim3(256), 0, stream>>>(
      rel_w, Relh, Rell, NLAY * NREL, HID);

  split_frag<IND><<<dim3(NGRP), dim3(256), 0, stream>>>(x, xh, xl);

  gemm_frag<IND><<<dim3(1, MB), dim3(256), 0, stream>>>(
      xh, xl, Wph, Wpl, bp, h, (ushort*)nullptr, 128, NN);
  split_frag<HID><<<dim3(NGRP), dim3(256), 0, stream>>>(h, hh, hl);

  for (int l = 0; l < NLAY; ++l) {
    gemm_frag<HID><<<dim3(1, MB), dim3(256), 0, stream>>>(
        hh, hl, Rth + (size_t)l * HID * HID, Rtl + (size_t)l * HID * HID,
        conv_b + (size_t)l * HID, OUT, (ushort*)nullptr, 128, NN);
    for (int p = 0; p < P; ++p) {
      gemm_frag<HID><<<dim3(G, MB), dim3(256), 0, stream>>>(
          hh, hl, Relh + ((size_t)l * NREL + (size_t)p * G) * HID * HID,
          Rell + ((size_t)l * NREL + (size_t)p * G) * HID * HID,
          (const float*)nullptr, (float*)nullptr, T, G * HID, NN);
      aggregate<<<dim3(NN / 4), dim3(256), 0, stream>>>(
          eids, rowstart, srcv, et, winv, T, OUT, p * G, G);
    }
    ln_relu_res_frag<<<dim3(NGRP), dim3(256), 0, stream>>>(
        OUT, h, ln_g + (size_t)l * HID, ln_b + (size_t)l * HID, hh, hl);
  }

  pool_kernel<<<dim3((NN + 63) / 64), dim3(128), 0, stream>>>(h, batch, out);
}

// Round 4
// 1084.349 us; speedup vs baseline: 2.7248x; 1.5011x over previous
//
#include <hip/hip_runtime.h>

#define NN 50000
#define NE 600000
#define IND 64
#define HID 128
#define NREL 10
#define NLAY 6
#define NG 64
#define LN_EPS 1e-5f
#define NMAT 11  // 10 rel + 1 root per layer, packed

typedef __attribute__((ext_vector_type(8))) short bf8;
typedef __attribute__((ext_vector_type(4))) float f4;

__device__ __forceinline__ ushort f2bf(float x) {
  uint u = __float_as_uint(x);
  u += 0x7fff + ((u >> 16) & 1);
  return (ushort)(u >> 16);
}
__device__ __forceinline__ float bf2f(ushort h) {
  return __uint_as_float(((uint)h) << 16);
}

// ---------------------------------------------------------------- utilities
__global__ void zero_kernel(float* __restrict__ p, int n) {
  int i = blockIdx.x * blockDim.x + threadIdx.x;
  int stride = gridDim.x * blockDim.x;
  for (; i < n; i += stride) p[i] = 0.f;
}

__global__ void count_edges(const int* __restrict__ dst, const int* __restrict__ et,
                            float* __restrict__ winv, int* __restrict__ deg) {
  int e = blockIdx.x * 256 + threadIdx.x;
  if (e >= NE) return;
  int d = dst[e];
  atomicAdd(&winv[d * NREL + et[e]], 1.0f);
  atomicAdd(&deg[d], 1);
}

__global__ void invert_winv(float* __restrict__ winv) {
  int i = blockIdx.x * 256 + threadIdx.x;
  if (i < NN * NREL) winv[i] = 1.0f / fmaxf(winv[i], 1.0f);
}

__global__ void scan_block(const int* __restrict__ deg, int* __restrict__ rowstart,
                           int* __restrict__ partial) {
  __shared__ int sh[256];
  int i = blockIdx.x * 256 + threadIdx.x;
  int v = (i < NN) ? deg[i] : 0;
  sh[threadIdx.x] = v;
  __syncthreads();
  int x = v;
  for (int off = 1; off < 256; off <<= 1) {
    int y = (threadIdx.x >= off) ? sh[threadIdx.x - off] : 0;
    __syncthreads();
    x += y;
    sh[threadIdx.x] = x;
    __syncthreads();
  }
  if (i < NN) rowstart[i] = x - v;
  if (threadIdx.x == 255) partial[blockIdx.x] = x;
}

__global__ void scan_partials(int* __restrict__ partial, int nb) {
  __shared__ int sh[256];
  int v = (threadIdx.x < nb) ? partial[threadIdx.x] : 0;
  sh[threadIdx.x] = v;
  __syncthreads();
  int x = v;
  for (int off = 1; off < 256; off <<= 1) {
    int y = (threadIdx.x >= off) ? sh[threadIdx.x - off] : 0;
    __syncthreads();
    x += y;
    sh[threadIdx.x] = x;
    __syncthreads();
  }
  partial[threadIdx.x] = x - v;
}

__global__ void scan_add(int* __restrict__ rowstart, const int* __restrict__ partial) {
  int i = blockIdx.x * 256 + threadIdx.x;
  if (i < NN) rowstart[i] += partial[i >> 8];
  if (i == 0) rowstart[NN] = NE;
}

// CSR fill with precomputed packed (src,type) and per-edge scale winv[dst,type]
__global__ void fill_csr(const int* __restrict__ dst, const int* __restrict__ src,
                         const int* __restrict__ et, int* __restrict__ fillpos,
                         const int* __restrict__ rowstart, const float* __restrict__ winv,
                         int* __restrict__ pkd, float* __restrict__ wsc) {
  int e = blockIdx.x * 256 + threadIdx.x;
  if (e >= NE) return;
  int d = dst[e], t = et[e];
  int pos = rowstart[d] + atomicAdd(&fillpos[d], 1);
  pkd[pos] = (src[e] << 4) | t;
  wsc[pos] = winv[d * NREL + t];
}

// ------------------------------------------------------------- weight prep
// src: nmat [K][128] fp32 -> fragment-linear bf16 hi/lo at dest mat
// index (m/ddiv)*dmul + (m%ddiv) + dadd.
__global__ void transpose_split_frag(const float* __restrict__ src, ushort* __restrict__ dh,
                                     ushort* __restrict__ dl, int nmat, int K,
                                     int ddiv, int dmul, int dadd) {
  int i = blockIdx.x * 256 + threadIdx.x;
  int tot = nmat * K * 128;
  if (i >= tot) return;
  int m = i / (K * 128);
  int rem = i - m * (K * 128);
  int k = rem / 128;
  int n = rem - k * 128;
  float v = src[i];
  ushort h = f2bf(v);
  int dm = (m / ddiv) * dmul + (m % ddiv) + dadd;
  size_t o = (size_t)dm * (K * 128) + (size_t)(n >> 4) * (K * 16) + (k >> 3) * 128 +
             (n & 15) * 8 + (k & 7);
  dh[o] = h;
  dl[o] = f2bf(v - bf2f(h));
}

// rows fp32 [N][K] -> fragment-linear bf16 hi/lo, one 16-row group per block
template <int K>
__global__ __launch_bounds__(256) void split_frag(const float* __restrict__ src,
                                                  ushort* __restrict__ dh,
                                                  ushort* __restrict__ dl) {
  constexpr int TOT = 16 * K;
  __shared__ ushort sh[TOT], sl[TOT];
  int grp = blockIdx.x;
  const float* s = src + (size_t)grp * TOT;
  for (int i = threadIdx.x * 4; i < TOT; i += 1024) {
    float4 v = *(const float4*)(s + i);
    int nl = i / K, d = i - nl * K;
    int off = (d >> 3) * 128 + nl * 8 + (d & 7);
    ushort h0 = f2bf(v.x), h1 = f2bf(v.y), h2 = f2bf(v.z), h3 = f2bf(v.w);
    *(uint*)(sh + off) = (uint)h0 | ((uint)h1 << 16);
    *(uint*)(sh + off + 2) = (uint)h2 | ((uint)h3 << 16);
    *(uint*)(sl + off) = (uint)f2bf(v.x - bf2f(h0)) | ((uint)f2bf(v.y - bf2f(h1)) << 16);
    *(uint*)(sl + off + 2) = (uint)f2bf(v.z - bf2f(h2)) | ((uint)f2bf(v.w - bf2f(h3)) << 16);
  }
  __syncthreads();
  size_t base = (size_t)grp * TOT;
  for (int i = threadIdx.x * 8; i < TOT; i += 2048) {
    *(bf8*)(dh + base + i) = *(const bf8*)(sh + i);
    *(bf8*)(dl + base + i) = *(const bf8*)(sl + i);
  }
}

// ----------------------------------------------------- LDS-free bf16x3 GEMM
struct Frags {
  bf8 ah[4], al[4], bh[4], bl[4];
};

template <int K>
__device__ __forceinline__ void load_frags(Frags& f, int ks, const ushort* Abh,
                                           const ushort* Abl, const ushort* Bbh,
                                           const ushort* Bbl) {
#pragma unroll
  for (int m = 0; m < 4; ++m) {
    f.ah[m] = *(const bf8*)(Abh + (size_t)m * (K * 16) + ks * 512);
    f.al[m] = *(const bf8*)(Abl + (size_t)m * (K * 16) + ks * 512);
  }
#pragma unroll
  for (int n = 0; n < 4; ++n) {
    f.bh[n] = *(const bf8*)(Bbh + (size_t)n * (K * 16) + ks * 512);
    f.bl[n] = *(const bf8*)(Bbl + (size_t)n * (K * 16) + ks * 512);
  }
}

__device__ __forceinline__ void mfma_frags(f4 (&acc)[4][4], const Frags& f) {
#pragma unroll
  for (int m = 0; m < 4; ++m)
#pragma unroll
    for (int n = 0; n < 4; ++n) {
      acc[m][n] = __builtin_amdgcn_mfma_f32_16x16x32_bf16(f.ah[m], f.bh[n], acc[m][n], 0, 0, 0);
      acc[m][n] = __builtin_amdgcn_mfma_f32_16x16x32_bf16(f.al[m], f.bh[n], acc[m][n], 0, 0, 0);
      acc[m][n] = __builtin_amdgcn_mfma_f32_16x16x32_bf16(f.ah[m], f.bl[n], acc[m][n], 0, 0, 0);
    }
}

// Fused GEMM: bx<nrel -> Cb (bf16, T at col-block bx); bx==nrel -> Cf fp32 + bias.
template <int K>
__global__ __launch_bounds__(256) void gemm_frag(
    const ushort* __restrict__ Ah, const ushort* __restrict__ Al,
    const ushort* __restrict__ Bh, const ushort* __restrict__ Bl,
    const float* __restrict__ bias, float* __restrict__ Cf, ushort* __restrict__ Cb,
    int ldc, int M, int nrel) {
  int nwg = gridDim.x * gridDim.y;
  int lin = blockIdx.y * gridDim.x + blockIdx.x;
  int q = nwg >> 3, r8 = nwg & 7;
  int xcd = lin & 7, sub = lin >> 3;
  int swz = (xcd < r8) ? (xcd * (q + 1) + sub) : (r8 * (q + 1) + (xcd - r8) * q + sub);
  int bx = swz % gridDim.x;
  int by = swz / gridDim.x;

  const int bm = by * 128;
  const int tid = threadIdx.x, w = tid >> 6, lane = tid & 63;
  const int wr = (w >> 1) * 64, wc = (w & 1) * 64;
  const int lr = lane & 15;

  const ushort* Abh = Ah + ((size_t)(bm >> 4) + (wr >> 4)) * (K * 16) + lane * 8;
  const ushort* Abl = Al + ((size_t)(bm >> 4) + (wr >> 4)) * (K * 16) + lane * 8;
  const ushort* Bbh = Bh + (size_t)bx * (128 * K) + (size_t)(wc >> 4) * (K * 16) + lane * 8;
  const ushort* Bbl = Bl + (size_t)bx * (128 * K) + (size_t)(wc >> 4) * (K * 16) + lane * 8;

  f4 acc[4][4] = {};
  Frags fa, fb;
  if constexpr (K == 64) {
    load_frags<K>(fa, 0, Abh, Abl, Bbh, Bbl);
    load_frags<K>(fb, 1, Abh, Abl, Bbh, Bbl);
    mfma_frags(acc, fa);
    mfma_frags(acc, fb);
  } else {
    load_frags<K>(fa, 0, Abh, Abl, Bbh, Bbl);
    load_frags<K>(fb, 1, Abh, Abl, Bbh, Bbl);
    mfma_frags(acc, fa);
    load_frags<K>(fa, 2, Abh, Abl, Bbh, Bbl);
    mfma_frags(acc, fb);
    load_frags<K>(fb, 3, Abh, Abl, Bbh, Bbl);
    mfma_frags(acc, fa);
    mfma_frags(acc, fb);
  }

  const bool isroot = (bx == nrel);
  const int rgrp = (lane >> 4) * 4;
#pragma unroll
  for (int n = 0; n < 4; ++n) {
    int col = wc + n * 16 + lr;
    float bv = isroot ? bias[col] : 0.f;
#pragma unroll
    for (int m = 0; m < 4; ++m) {
      int r0 = bm + wr + m * 16 + rgrp;
#pragma unroll
      for (int j = 0; j < 4; ++j) {
        int r = r0 + j;
        if (r < M) {
          float v = acc[m][n][j];
          if (isroot) Cf[(size_t)r * 128 + col] = v + bv;
          else Cb[(size_t)r * ldc + bx * 128 + col] = f2bf(v);
        }
      }
    }
  }
}

// ------------------------------------------------------- CSR mean-aggregate
// 8-deep unrolled independent gathers; pkd/wsc precomputed -> no load chain.
__global__ __launch_bounds__(256) void aggregate(
    const int* __restrict__ pkd, const float* __restrict__ wsc,
    const int* __restrict__ rowstart, const ushort* __restrict__ T,
    float* __restrict__ OUT, int r0, int G) {
  int node = blockIdx.x * 4 + (threadIdx.x >> 6);
  if (node >= NN) return;
  int lane = threadIdx.x & 63;
  int e0 = rowstart[node], e1 = rowstart[node + 1];
  const int TW = G * HID;
  const int lo = lane * 2;
  float ax = 0.f, ay = 0.f;
  int p = e0;
  constexpr int U = 8;
  for (; p + U <= e1; p += U) {
    int pk[U];
    float wg[U];
    size_t ad[U];
#pragma unroll
    for (int u = 0; u < U; ++u) {
      pk[u] = pkd[p + u];
      wg[u] = wsc[p + u];
    }
#pragma unroll
    for (int u = 0; u < U; ++u) {
      int t = (pk[u] & 15) - r0;
      bool ok = (unsigned)t < (unsigned)G;
      ad[u] = ok ? ((size_t)(pk[u] >> 4) * TW + t * HID) : 0;
      if (!ok) wg[u] = 0.f;
    }
    uint v[U];
#pragma unroll
    for (int u = 0; u < U; ++u) v[u] = *(const uint*)(T + ad[u] + lo);
#pragma unroll
    for (int u = 0; u < U; ++u) {
      ax += wg[u] * bf2f((ushort)(v[u] & 0xffffu));
      ay += wg[u] * bf2f((ushort)(v[u] >> 16));
    }
  }
  for (; p < e1; ++p) {
    int pk = pkd[p];
    float wg = wsc[p];
    int t = (pk & 15) - r0;
    if ((unsigned)t < (unsigned)G) {
      uint v = *(const uint*)(T + (size_t)(pk >> 4) * TW + t * HID + lo);
      ax += wg * bf2f((ushort)(v & 0xffffu));
      ay += wg * bf2f((ushort)(v >> 16));
    }
  }
  float2* o = (float2*)(OUT + (size_t)node * HID + lo);
  float2 cur = *o;
  cur.x += ax;
  cur.y += ay;
  *o = cur;
}

// --------------------- LN + ReLU + residual + fragment-linear bf16 split out
__global__ __launch_bounds__(256) void ln_relu_res_frag(
    const float* __restrict__ OUT, float* __restrict__ h,
    const float* __restrict__ g, const float* __restrict__ b,
    ushort* __restrict__ dh, ushort* __restrict__ dl) {
  __shared__ ushort sh[2048], sl[2048];
  int grp = blockIdx.x;
  int w = threadIdx.x >> 6, lane = threadIdx.x & 63;
  float2 gg = *(const float2*)(g + lane * 2);
  float2 bb = *(const float2*)(b + lane * 2);
#pragma unroll
  for (int p = 0; p < 4; ++p) {
    int r = w * 4 + p;
    int node = grp * 16 + r;
    float2 v = *(const float2*)(OUT + (size_t)node * HID + lane * 2);
    float s = v.x + v.y, sq = v.x * v.x + v.y * v.y;
#pragma unroll
    for (int off = 32; off; off >>= 1) {
      s += __shfl_xor(s, off);
      sq += __shfl_xor(sq, off);
    }
    float mu = s * (1.f / HID);
    float var = sq * (1.f / HID) - mu * mu;
    float rs = rsqrtf(var + LN_EPS);
    float2 rr = *(const float2*)(h + (size_t)node * HID + lane * 2);
    float y0 = fmaxf((v.x - mu) * rs * gg.x + bb.x, 0.f) + rr.x;
    float y1 = fmaxf((v.y - mu) * rs * gg.y + bb.y, 0.f) + rr.y;
    *(float2*)(h + (size_t)node * HID + lane * 2) = make_float2(y0, y1);
    int d = lane * 2;
    int off2 = (d >> 3) * 128 + r * 8 + (d & 7);
    ushort h0 = f2bf(y0), h1 = f2bf(y1);
    *(uint*)(sh + off2) = (uint)h0 | ((uint)h1 << 16);
    *(uint*)(sl + off2) =
        (uint)f2bf(y0 - bf2f(h0)) | ((uint)f2bf(y1 - bf2f(h1)) << 16);
  }
  __syncthreads();
  size_t base = (size_t)grp * 2048;
  int t8 = threadIdx.x * 8;
  *(bf8*)(dh + base + t8) = *(const bf8*)(sh + t8);
  *(bf8*)(dl + base + t8) = *(const bf8*)(sl + t8);
}

// ---------------------------------------------------------------- pooling
__global__ void pool_kernel(const float* __restrict__ h, const int* __restrict__ batch,
                            float* __restrict__ out) {
  int n0 = blockIdx.x * 64;
  if (n0 >= NN) return;
  int t = threadIdx.x;
  int nend = min(n0 + 64, NN);
  int cur = batch[n0];
  float acc = 0.f;
  for (int n = n0; n < nend; ++n) {
    int gph = batch[n];
    if (gph != cur) {
      atomicAdd(&out[cur * HID + t], acc);
      acc = 0.f;
      cur = gph;
    }
    acc += h[(size_t)n * HID + t];
  }
  atomicAdd(&out[cur * HID + t], acc);
}

// ---------------------------------------------------------------- launch
extern "C" void kernel_launch(void* const* d_in, const int* in_sizes, int n_in,
                              void* d_out, int out_size, void* d_ws, size_t ws_size,
                              hipStream_t stream) {
  const float* x = (const float*)d_in[0];
  const int* ei = (const int*)d_in[1];
  const int* et = (const int*)d_in[2];
  const int* batch = (const int*)d_in[3];
  const float* Wp = (const float*)d_in[4];
  const float* bp = (const float*)d_in[5];
  const float* rel_w = (const float*)d_in[6];
  const float* root_w = (const float*)d_in[7];
  const float* conv_b = (const float*)d_in[8];
  const float* ln_g = (const float*)d_in[9];
  const float* ln_b = (const float*)d_in[10];
  float* out = (float*)d_out;
  const int* srcv = ei;
  const int* dstv = ei + NE;

  const int NGRP = NN / 16;       // 3125
  const int NGRP_PAD = NGRP + 3;  // GEMM reads up to group 3127

  char* w = (char*)d_ws;
  auto alloc = [&](size_t bytes) {
    char* p = w;
    w += (bytes + 255) & ~(size_t)255;
    return p;
  };
  float* h = (float*)alloc((size_t)NN * HID * 4);
  float* OUT = (float*)alloc((size_t)NN * HID * 4);
  float* winv = (float*)alloc((size_t)NN * NREL * 4);
  int* deg = (int*)alloc((size_t)NN * 4);
  int* rowstart = (int*)alloc((size_t)(NN + 1) * 4);
  int* fillpos = (int*)alloc((size_t)NN * 4);
  int* pkd = (int*)alloc((size_t)NE * 4);
  float* wsc = (float*)alloc((size_t)NE * 4);
  int* partial = (int*)alloc(256 * 4);
  ushort* xh = (ushort*)alloc((size_t)NGRP_PAD * 1024 * 2);
  ushort* xl = (ushort*)alloc((size_t)NGRP_PAD * 1024 * 2);
  ushort* hh = (ushort*)alloc((size_t)NGRP_PAD * 2048 * 2);
  ushort* hl = (ushort*)alloc((size_t)NGRP_PAD * 2048 * 2);
  ushort* Wph = (ushort*)alloc((size_t)IND * HID * 2);
  ushort* Wpl = (ushort*)alloc((size_t)IND * HID * 2);
  ushort* Relh = (ushort*)alloc((size_t)NLAY * NMAT * HID * HID * 2);
  ushort* Rell = (ushort*)alloc((size_t)NLAY * NMAT * HID * HID * 2);

  size_t used = (size_t)(w - (char*)d_ws);
  size_t rem = (ws_size > used) ? ws_size - used : 0;
  int G = 1;
  if (rem >= (size_t)NN * 10 * HID * 2) G = 10;
  else if (rem >= (size_t)NN * 5 * HID * 2) G = 5;
  else if (rem >= (size_t)NN * 2 * HID * 2) G = 2;
  ushort* T = (ushort*)alloc((size_t)NN * G * HID * 2);
  const int P = NREL / G;

  const int NB_E = (NE + 255) / 256;
  const int NB_N = (NN + 255) / 256;
  const int MB = (NN + 127) / 128;  // 391

  zero_kernel<<<dim3(512), dim3(256), 0, stream>>>(winv, NN * NREL);
  zero_kernel<<<dim3(256), dim3(256), 0, stream>>>((float*)deg, NN);
  zero_kernel<<<dim3(256), dim3(256), 0, stream>>>((float*)fillpos, NN);
  zero_kernel<<<dim3(32), dim3(256), 0, stream>>>(out, NG * HID);

  count_edges<<<dim3(NB_E), dim3(256), 0, stream>>>(dstv, et, winv, deg);
  invert_winv<<<dim3((NN * NREL + 255) / 256), dim3(256), 0, stream>>>(winv);
  scan_block<<<dim3(NB_N), dim3(256), 0, stream>>>(deg, rowstart, partial);
  scan_partials<<<dim3(1), dim3(256), 0, stream>>>(partial, NB_N);
  scan_add<<<dim3(NB_N), dim3(256), 0, stream>>>(rowstart, partial);
  fill_csr<<<dim3(NB_E), dim3(256), 0, stream>>>(dstv, srcv, et, fillpos, rowstart,
                                                 winv, pkd, wsc);

  transpose_split_frag<<<dim3((IND * HID + 255) / 256), dim3(256), 0, stream>>>(
      Wp, Wph, Wpl, 1, IND, 1, 1, 0);
  transpose_split_frag<<<dim3((NLAY * NREL * HID * HID + 255) / 256), dim3(256), 0, stream>>>(
      rel_w, Relh, Rell, NLAY * NREL, HID, NREL, NMAT, 0);
  transpose_split_frag<<<dim3((NLAY * HID * HID + 255) / 256), dim3(256), 0, stream>>>(
      root_w, Relh, Rell, NLAY, HID, 1, NMAT, NREL);

  split_frag<IND><<<dim3(NGRP), dim3(256), 0, stream>>>(x, xh, xl);

  // projection: h = x @ Wp + bp  (bx==0==nrel -> fp32+bias path)
  gemm_frag<IND><<<dim3(1, MB), dim3(256), 0, stream>>>(
      xh, xl, Wph, Wpl, bp, h, (ushort*)nullptr, 128, NN, 0);
  split_frag<HID><<<dim3(NGRP), dim3(256), 0, stream>>>(h, hh, hl);

  for (int l = 0; l < NLAY; ++l) {
    const ushort* Bh = Relh + (size_t)l * NMAT * HID * HID;
    const ushort* Bl = Rell + (size_t)l * NMAT * HID * HID;
    if (G == NREL) {
      // fused: 10 rel blocks -> T, block 10 -> OUT=root+bias
      gemm_frag<HID><<<dim3(NREL + 1, MB), dim3(256), 0, stream>>>(
          hh, hl, Bh, Bl, conv_b + (size_t)l * HID, OUT, T, G * HID, NN, NREL);
      aggregate<<<dim3(NN / 4), dim3(256), 0, stream>>>(pkd, wsc, rowstart, T, OUT, 0, G);
    } else {
      gemm_frag<HID><<<dim3(1, MB), dim3(256), 0, stream>>>(
          hh, hl, Bh + (size_t)NREL * HID * HID, Bl + (size_t)NREL * HID * HID,
          conv_b + (size_t)l * HID, OUT, (ushort*)nullptr, 128, NN, 0);
      for (int p = 0; p < P; ++p) {
        gemm_frag<HID><<<dim3(G, MB), dim3(256), 0, stream>>>(
            hh, hl, Bh + (size_t)p * G * HID * HID, Bl + (size_t)p * G * HID * HID,
            (const float*)nullptr, (float*)nullptr, T, G * HID, NN, -1);
        aggregate<<<dim3(NN / 4), dim3(256), 0, stream>>>(pkd, wsc, rowstart, T, OUT,
                                                          p * G, G);
      }
    }
    ln_relu_res_frag<<<dim3(NGRP), dim3(256), 0, stream>>>(
        OUT, h, ln_g + (size_t)l * HID, ln_b + (size_t)l * HID, hh, hl);
  }

  pool_kernel<<<dim3((NN + 63) / 64), dim3(128), 0, stream>>>(h, batch, out);
}

// Round 5
// 909.388 us; speedup vs baseline: 3.2490x; 1.1924x over previous
//
#include <hip/hip_runtime.h>

#define NN 50000
#define NE 600000
#define IND 64
#define HID 128
#define NREL 10
#define NLAY 6
#define NG 64
#define LN_EPS 1e-5f
#define NMAT 11  // 10 rel + 1 root per layer, packed

typedef __attribute__((ext_vector_type(8))) short bf8;
typedef __attribute__((ext_vector_type(4))) float f4;

__device__ __forceinline__ ushort f2bf(float x) {
  uint u = __float_as_uint(x);
  u += 0x7fff + ((u >> 16) & 1);
  return (ushort)(u >> 16);
}
__device__ __forceinline__ float bf2f(ushort h) {
  return __uint_as_float(((uint)h) << 16);
}

// ---------------------------------------------------------------- utilities
__global__ void zero_kernel(float* __restrict__ p, int n) {
  int i = blockIdx.x * blockDim.x + threadIdx.x;
  int stride = gridDim.x * blockDim.x;
  for (; i < n; i += stride) p[i] = 0.f;
}

__global__ void count_edges(const int* __restrict__ dst, const int* __restrict__ et,
                            float* __restrict__ winv, int* __restrict__ deg) {
  int e = blockIdx.x * 256 + threadIdx.x;
  if (e >= NE) return;
  int d = dst[e];
  atomicAdd(&winv[d * NREL + et[e]], 1.0f);
  atomicAdd(&deg[d], 1);
}

__global__ void invert_winv(float* __restrict__ winv) {
  int i = blockIdx.x * 256 + threadIdx.x;
  if (i < NN * NREL) winv[i] = 1.0f / fmaxf(winv[i], 1.0f);
}

__global__ void scan_block(const int* __restrict__ deg, int* __restrict__ rowstart,
                           int* __restrict__ partial) {
  __shared__ int sh[256];
  int i = blockIdx.x * 256 + threadIdx.x;
  int v = (i < NN) ? deg[i] : 0;
  sh[threadIdx.x] = v;
  __syncthreads();
  int x = v;
  for (int off = 1; off < 256; off <<= 1) {
    int y = (threadIdx.x >= off) ? sh[threadIdx.x - off] : 0;
    __syncthreads();
    x += y;
    sh[threadIdx.x] = x;
    __syncthreads();
  }
  if (i < NN) rowstart[i] = x - v;
  if (threadIdx.x == 255) partial[blockIdx.x] = x;
}

__global__ void scan_partials(int* __restrict__ partial, int nb) {
  __shared__ int sh[256];
  int v = (threadIdx.x < nb) ? partial[threadIdx.x] : 0;
  sh[threadIdx.x] = v;
  __syncthreads();
  int x = v;
  for (int off = 1; off < 256; off <<= 1) {
    int y = (threadIdx.x >= off) ? sh[threadIdx.x - off] : 0;
    __syncthreads();
    x += y;
    sh[threadIdx.x] = x;
    __syncthreads();
  }
  partial[threadIdx.x] = x - v;
}

__global__ void scan_add(int* __restrict__ rowstart, const int* __restrict__ partial) {
  int i = blockIdx.x * 256 + threadIdx.x;
  if (i < NN) rowstart[i] += partial[i >> 8];
  if (i == 0) rowstart[NN] = NE;
}

// CSR fill with precomputed packed (src,type) and per-edge scale winv[dst,type]
__global__ void fill_csr(const int* __restrict__ dst, const int* __restrict__ src,
                         const int* __restrict__ et, int* __restrict__ fillpos,
                         const int* __restrict__ rowstart, const float* __restrict__ winv,
                         int* __restrict__ pkd, float* __restrict__ wsc) {
  int e = blockIdx.x * 256 + threadIdx.x;
  if (e >= NE) return;
  int d = dst[e], t = et[e];
  int pos = rowstart[d] + atomicAdd(&fillpos[d], 1);
  pkd[pos] = (src[e] << 4) | t;
  wsc[pos] = winv[d * NREL + t];
}

// ------------------------------------------------------------- weight prep
// src: nmat [K][128] fp32 -> fragment-linear bf16 hi/lo at dest mat
// index (m/ddiv)*dmul + (m%ddiv) + dadd.
__global__ void transpose_split_frag(const float* __restrict__ src, ushort* __restrict__ dh,
                                     ushort* __restrict__ dl, int nmat, int K,
                                     int ddiv, int dmul, int dadd) {
  int i = blockIdx.x * 256 + threadIdx.x;
  int tot = nmat * K * 128;
  if (i >= tot) return;
  int m = i / (K * 128);
  int rem = i - m * (K * 128);
  int k = rem / 128;
  int n = rem - k * 128;
  float v = src[i];
  ushort h = f2bf(v);
  int dm = (m / ddiv) * dmul + (m % ddiv) + dadd;
  size_t o = (size_t)dm * (K * 128) + (size_t)(n >> 4) * (K * 16) + (k >> 3) * 128 +
             (n & 15) * 8 + (k & 7);
  dh[o] = h;
  dl[o] = f2bf(v - bf2f(h));
}

// rows fp32 [N][K] -> fragment-linear bf16 hi/lo, one 16-row group per block
template <int K>
__global__ __launch_bounds__(256) void split_frag(const float* __restrict__ src,
                                                  ushort* __restrict__ dh,
                                                  ushort* __restrict__ dl) {
  constexpr int TOT = 16 * K;
  __shared__ ushort sh[TOT], sl[TOT];
  int grp = blockIdx.x;
  const float* s = src + (size_t)grp * TOT;
  for (int i = threadIdx.x * 4; i < TOT; i += 1024) {
    float4 v = *(const float4*)(s + i);
    int nl = i / K, d = i - nl * K;
    int off = (d >> 3) * 128 + nl * 8 + (d & 7);
    ushort h0 = f2bf(v.x), h1 = f2bf(v.y), h2 = f2bf(v.z), h3 = f2bf(v.w);
    *(uint*)(sh + off) = (uint)h0 | ((uint)h1 << 16);
    *(uint*)(sh + off + 2) = (uint)h2 | ((uint)h3 << 16);
    *(uint*)(sl + off) = (uint)f2bf(v.x - bf2f(h0)) | ((uint)f2bf(v.y - bf2f(h1)) << 16);
    *(uint*)(sl + off + 2) = (uint)f2bf(v.z - bf2f(h2)) | ((uint)f2bf(v.w - bf2f(h3)) << 16);
  }
  __syncthreads();
  size_t base = (size_t)grp * TOT;
  for (int i = threadIdx.x * 8; i < TOT; i += 2048) {
    *(bf8*)(dh + base + i) = *(const bf8*)(sh + i);
    *(bf8*)(dl + base + i) = *(const bf8*)(sl + i);
  }
}

// ----------------------------------------------------- LDS-free bf16x3 GEMM
struct Frags {
  bf8 ah[4], al[4], bh[4], bl[4];
};

template <int K>
__device__ __forceinline__ void load_frags(Frags& f, int ks, const ushort* Abh,
                                           const ushort* Abl, const ushort* Bbh,
                                           const ushort* Bbl) {
#pragma unroll
  for (int m = 0; m < 4; ++m) {
    f.ah[m] = *(const bf8*)(Abh + (size_t)m * (K * 16) + ks * 512);
    f.al[m] = *(const bf8*)(Abl + (size_t)m * (K * 16) + ks * 512);
  }
#pragma unroll
  for (int n = 0; n < 4; ++n) {
    f.bh[n] = *(const bf8*)(Bbh + (size_t)n * (K * 16) + ks * 512);
    f.bl[n] = *(const bf8*)(Bbl + (size_t)n * (K * 16) + ks * 512);
  }
}

__device__ __forceinline__ void mfma_frags(f4 (&acc)[4][4], const Frags& f) {
#pragma unroll
  for (int m = 0; m < 4; ++m)
#pragma unroll
    for (int n = 0; n < 4; ++n) {
      acc[m][n] = __builtin_amdgcn_mfma_f32_16x16x32_bf16(f.ah[m], f.bh[n], acc[m][n], 0, 0, 0);
      acc[m][n] = __builtin_amdgcn_mfma_f32_16x16x32_bf16(f.al[m], f.bh[n], acc[m][n], 0, 0, 0);
      acc[m][n] = __builtin_amdgcn_mfma_f32_16x16x32_bf16(f.ah[m], f.bl[n], acc[m][n], 0, 0, 0);
    }
}

// Fused GEMM: bx<nrel -> Cb (bf16 T, LDS-staged coalesced); bx==nrel -> Cf fp32+bias.
template <int K>
__global__ __launch_bounds__(256) void gemm_frag(
    const ushort* __restrict__ Ah, const ushort* __restrict__ Al,
    const ushort* __restrict__ Bh, const ushort* __restrict__ Bl,
    const float* __restrict__ bias, float* __restrict__ Cf, ushort* __restrict__ Cb,
    int ldc, int M, int nrel) {
  __shared__ ushort st[128][136];  // +16B row pad: conflict-light stage
  int nwg = gridDim.x * gridDim.y;
  int lin = blockIdx.y * gridDim.x + blockIdx.x;
  int q = nwg >> 3, r8 = nwg & 7;
  int xcd = lin & 7, sub = lin >> 3;
  int swz = (xcd < r8) ? (xcd * (q + 1) + sub) : (r8 * (q + 1) + (xcd - r8) * q + sub);
  int bx = swz % gridDim.x;
  int by = swz / gridDim.x;

  const int bm = by * 128;
  const int tid = threadIdx.x, w = tid >> 6, lane = tid & 63;
  const int wr = (w >> 1) * 64, wc = (w & 1) * 64;
  const int lr = lane & 15;

  const ushort* Abh = Ah + ((size_t)(bm >> 4) + (wr >> 4)) * (K * 16) + lane * 8;
  const ushort* Abl = Al + ((size_t)(bm >> 4) + (wr >> 4)) * (K * 16) + lane * 8;
  const ushort* Bbh = Bh + (size_t)bx * (128 * K) + (size_t)(wc >> 4) * (K * 16) + lane * 8;
  const ushort* Bbl = Bl + (size_t)bx * (128 * K) + (size_t)(wc >> 4) * (K * 16) + lane * 8;

  f4 acc[4][4] = {};
  Frags fa, fb;
  if constexpr (K == 64) {
    load_frags<K>(fa, 0, Abh, Abl, Bbh, Bbl);
    load_frags<K>(fb, 1, Abh, Abl, Bbh, Bbl);
    mfma_frags(acc, fa);
    mfma_frags(acc, fb);
  } else {
    load_frags<K>(fa, 0, Abh, Abl, Bbh, Bbl);
    load_frags<K>(fb, 1, Abh, Abl, Bbh, Bbl);
    mfma_frags(acc, fa);
    load_frags<K>(fa, 2, Abh, Abl, Bbh, Bbl);
    mfma_frags(acc, fb);
    load_frags<K>(fb, 3, Abh, Abl, Bbh, Bbl);
    mfma_frags(acc, fa);
    mfma_frags(acc, fb);
  }

  const int rgrp = (lane >> 4) * 4;
  if (bx == nrel) {
    // root / projection: direct fp32 + bias (64B-per-row runs, coalesced enough)
#pragma unroll
    for (int n = 0; n < 4; ++n) {
      int col = wc + n * 16 + lr;
      float bv = bias[col];
#pragma unroll
      for (int m = 0; m < 4; ++m) {
        int r0 = bm + wr + m * 16 + rgrp;
#pragma unroll
        for (int j = 0; j < 4; ++j) {
          int r = r0 + j;
          if (r < M) Cf[(size_t)r * 128 + col] = acc[m][n][j] + bv;
        }
      }
    }
  } else {
    // bf16 T tile: stage in LDS, then fully-coalesced 16B/lane stores
#pragma unroll
    for (int n = 0; n < 4; ++n) {
      int col = wc + n * 16 + lr;
#pragma unroll
      for (int m = 0; m < 4; ++m) {
        int r0 = wr + m * 16 + rgrp;
#pragma unroll
        for (int j = 0; j < 4; ++j) st[r0 + j][col] = f2bf(acc[m][n][j]);
      }
    }
    __syncthreads();
    const int rr = tid >> 4;        // 0..15
    const int cc = (tid & 15) * 8;  // ushort offset within row
#pragma unroll
    for (int it = 0; it < 8; ++it) {
      int row = it * 16 + rr;
      int grow = bm + row;
      if (grow < M) {
        bf8 v = *(const bf8*)&st[row][cc];
        *(bf8*)(Cb + (size_t)grow * ldc + bx * 128 + cc) = v;
      }
    }
  }
}

// ---------------- fused: mean-aggregate + root + LN + ReLU + residual + split
// Requires T full-width (G==NREL). Block = 16 nodes, wave handles 4 nodes.
__global__ __launch_bounds__(256) void agg_ln(
    const int* __restrict__ pkd, const float* __restrict__ wsc,
    const int* __restrict__ rowstart, const ushort* __restrict__ T,
    const float* __restrict__ OUT, float* __restrict__ h,
    const float* __restrict__ g, const float* __restrict__ b,
    ushort* __restrict__ dh, ushort* __restrict__ dl, int writeSplit) {
  __shared__ ushort sh[2048], sl[2048];
  const int grp = blockIdx.x;
  const int w = threadIdx.x >> 6, lane = threadIdx.x & 63;
  const int lo = lane * 2;
  float2 gg = *(const float2*)(g + lo);
  float2 bb = *(const float2*)(b + lo);
  constexpr int TW = NREL * HID;
#pragma unroll
  for (int p4 = 0; p4 < 4; ++p4) {
    int r = w * 4 + p4;
    int node = grp * 16 + r;
    float2 rt = *(const float2*)(OUT + (size_t)node * HID + lo);  // root + bias
    float ax = 0.f, ay = 0.f;
    int e0 = rowstart[node], e1 = rowstart[node + 1];
    int p = e0;
    constexpr int U = 8;
    for (; p + U <= e1; p += U) {
      int pk[U];
      float wg[U];
      uint v[U];
#pragma unroll
      for (int u = 0; u < U; ++u) {
        pk[u] = pkd[p + u];
        wg[u] = wsc[p + u];
      }
#pragma unroll
      for (int u = 0; u < U; ++u)
        v[u] = *(const uint*)(T + (size_t)(pk[u] >> 4) * TW + (pk[u] & 15) * HID + lo);
#pragma unroll
      for (int u = 0; u < U; ++u) {
        ax += wg[u] * bf2f((ushort)(v[u] & 0xffffu));
        ay += wg[u] * bf2f((ushort)(v[u] >> 16));
      }
    }
    for (; p < e1; ++p) {
      int pk = pkd[p];
      float wg = wsc[p];
      uint v = *(const uint*)(T + (size_t)(pk >> 4) * TW + (pk & 15) * HID + lo);
      ax += wg * bf2f((ushort)(v & 0xffffu));
      ay += wg * bf2f((ushort)(v >> 16));
    }
    float vx = rt.x + ax, vy = rt.y + ay;
    float s = vx + vy, sq = vx * vx + vy * vy;
#pragma unroll
    for (int off = 32; off; off >>= 1) {
      s += __shfl_xor(s, off);
      sq += __shfl_xor(sq, off);
    }
    float mu = s * (1.f / HID);
    float var = sq * (1.f / HID) - mu * mu;
    float rs = rsqrtf(var + LN_EPS);
    float2 rr2 = *(const float2*)(h + (size_t)node * HID + lo);
    float y0 = fmaxf((vx - mu) * rs * gg.x + bb.x, 0.f) + rr2.x;
    float y1 = fmaxf((vy - mu) * rs * gg.y + bb.y, 0.f) + rr2.y;
    *(float2*)(h + (size_t)node * HID + lo) = make_float2(y0, y1);
    int off2 = (lo >> 3) * 128 + r * 8 + (lo & 7);
    ushort h0 = f2bf(y0), h1 = f2bf(y1);
    *(uint*)(sh + off2) = (uint)h0 | ((uint)h1 << 16);
    *(uint*)(sl + off2) = (uint)f2bf(y0 - bf2f(h0)) | ((uint)f2bf(y1 - bf2f(h1)) << 16);
  }
  __syncthreads();
  if (writeSplit) {
    size_t base = (size_t)grp * 2048;
    int t8 = threadIdx.x * 8;
    *(bf8*)(dh + base + t8) = *(const bf8*)(sh + t8);
    *(bf8*)(dl + base + t8) = *(const bf8*)(sl + t8);
  }
}

// ---------------------------- fallback (G<NREL): separate aggregate + LN
__global__ __launch_bounds__(256) void aggregate(
    const int* __restrict__ pkd, const float* __restrict__ wsc,
    const int* __restrict__ rowstart, const ushort* __restrict__ T,
    float* __restrict__ OUT, int r0, int G) {
  int node = blockIdx.x * 4 + (threadIdx.x >> 6);
  if (node >= NN) return;
  int lane = threadIdx.x & 63;
  int e0 = rowstart[node], e1 = rowstart[node + 1];
  const int TW = G * HID;
  const int lo = lane * 2;
  float ax = 0.f, ay = 0.f;
  int p = e0;
  constexpr int U = 8;
  for (; p + U <= e1; p += U) {
    int pk[U];
    float wg[U];
    size_t ad[U];
#pragma unroll
    for (int u = 0; u < U; ++u) {
      pk[u] = pkd[p + u];
      wg[u] = wsc[p + u];
    }
#pragma unroll
    for (int u = 0; u < U; ++u) {
      int t = (pk[u] & 15) - r0;
      bool ok = (unsigned)t < (unsigned)G;
      ad[u] = ok ? ((size_t)(pk[u] >> 4) * TW + t * HID) : 0;
      if (!ok) wg[u] = 0.f;
    }
    uint v[U];
#pragma unroll
    for (int u = 0; u < U; ++u) v[u] = *(const uint*)(T + ad[u] + lo);
#pragma unroll
    for (int u = 0; u < U; ++u) {
      ax += wg[u] * bf2f((ushort)(v[u] & 0xffffu));
      ay += wg[u] * bf2f((ushort)(v[u] >> 16));
    }
  }
  for (; p < e1; ++p) {
    int pk = pkd[p];
    float wg = wsc[p];
    int t = (pk & 15) - r0;
    if ((unsigned)t < (unsigned)G) {
      uint v = *(const uint*)(T + (size_t)(pk >> 4) * TW + t * HID + lo);
      ax += wg * bf2f((ushort)(v & 0xffffu));
      ay += wg * bf2f((ushort)(v >> 16));
    }
  }
  float2* o = (float2*)(OUT + (size_t)node * HID + lo);
  float2 cur = *o;
  cur.x += ax;
  cur.y += ay;
  *o = cur;
}

__global__ __launch_bounds__(256) void ln_relu_res_frag(
    const float* __restrict__ OUT, float* __restrict__ h,
    const float* __restrict__ g, const float* __restrict__ b,
    ushort* __restrict__ dh, ushort* __restrict__ dl) {
  __shared__ ushort sh[2048], sl[2048];
  int grp = blockIdx.x;
  int w = threadIdx.x >> 6, lane = threadIdx.x & 63;
  float2 gg = *(const float2*)(g + lane * 2);
  float2 bb = *(const float2*)(b + lane * 2);
#pragma unroll
  for (int p = 0; p < 4; ++p) {
    int r = w * 4 + p;
    int node = grp * 16 + r;
    float2 v = *(const float2*)(OUT + (size_t)node * HID + lane * 2);
    float s = v.x + v.y, sq = v.x * v.x + v.y * v.y;
#pragma unroll
    for (int off = 32; off; off >>= 1) {
      s += __shfl_xor(s, off);
      sq += __shfl_xor(sq, off);
    }
    float mu = s * (1.f / HID);
    float var = sq * (1.f / HID) - mu * mu;
    float rs = rsqrtf(var + LN_EPS);
    float2 rr = *(const float2*)(h + (size_t)node * HID + lane * 2);
    float y0 = fmaxf((v.x - mu) * rs * gg.x + bb.x, 0.f) + rr.x;
    float y1 = fmaxf((v.y - mu) * rs * gg.y + bb.y, 0.f) + rr.y;
    *(float2*)(h + (size_t)node * HID + lane * 2) = make_float2(y0, y1);
    int d = lane * 2;
    int off2 = (d >> 3) * 128 + r * 8 + (d & 7);
    ushort h0 = f2bf(y0), h1 = f2bf(y1);
    *(uint*)(sh + off2) = (uint)h0 | ((uint)h1 << 16);
    *(uint*)(sl + off2) = (uint)f2bf(y0 - bf2f(h0)) | ((uint)f2bf(y1 - bf2f(h1)) << 16);
  }
  __syncthreads();
  size_t base = (size_t)grp * 2048;
  int t8 = threadIdx.x * 8;
  *(bf8*)(dh + base + t8) = *(const bf8*)(sh + t8);
  *(bf8*)(dl + base + t8) = *(const bf8*)(sl + t8);
}

// ---------------------------------------------------------------- pooling
__global__ void pool_kernel(const float* __restrict__ h, const int* __restrict__ batch,
                            float* __restrict__ out) {
  int n0 = blockIdx.x * 64;
  if (n0 >= NN) return;
  int t = threadIdx.x;
  int nend = min(n0 + 64, NN);
  int cur = batch[n0];
  float acc = 0.f;
  for (int n = n0; n < nend; ++n) {
    int gph = batch[n];
    if (gph != cur) {
      atomicAdd(&out[cur * HID + t], acc);
      acc = 0.f;
      cur = gph;
    }
    acc += h[(size_t)n * HID + t];
  }
  atomicAdd(&out[cur * HID + t], acc);
}

// ---------------------------------------------------------------- launch
extern "C" void kernel_launch(void* const* d_in, const int* in_sizes, int n_in,
                              void* d_out, int out_size, void* d_ws, size_t ws_size,
                              hipStream_t stream) {
  const float* x = (const float*)d_in[0];
  const int* ei = (const int*)d_in[1];
  const int* et = (const int*)d_in[2];
  const int* batch = (const int*)d_in[3];
  const float* Wp = (const float*)d_in[4];
  const float* bp = (const float*)d_in[5];
  const float* rel_w = (const float*)d_in[6];
  const float* root_w = (const float*)d_in[7];
  const float* conv_b = (const float*)d_in[8];
  const float* ln_g = (const float*)d_in[9];
  const float* ln_b = (const float*)d_in[10];
  float* out = (float*)d_out;
  const int* srcv = ei;
  const int* dstv = ei + NE;

  const int NGRP = NN / 16;       // 3125
  const int NGRP_PAD = NGRP + 3;  // GEMM reads up to group 3127

  char* w = (char*)d_ws;
  auto alloc = [&](size_t bytes) {
    char* p = w;
    w += (bytes + 255) & ~(size_t)255;
    return p;
  };
  float* h = (float*)alloc((size_t)NN * HID * 4);
  float* OUT = (float*)alloc((size_t)NN * HID * 4);
  // zero-span: winv .. fillpos (contiguous allocs; rowstart zeroing is harmless)
  float* winv = (float*)alloc((size_t)NN * NREL * 4);
  int* deg = (int*)alloc((size_t)NN * 4);
  int* rowstart = (int*)alloc((size_t)(NN + 1) * 4);
  int* fillpos = (int*)alloc((size_t)NN * 4);
  char* zend = w;
  int* pkd = (int*)alloc((size_t)NE * 4);
  float* wsc = (float*)alloc((size_t)NE * 4);
  int* partial = (int*)alloc(256 * 4);
  ushort* xh = (ushort*)alloc((size_t)NGRP_PAD * 1024 * 2);
  ushort* xl = (ushort*)alloc((size_t)NGRP_PAD * 1024 * 2);
  ushort* hh = (ushort*)alloc((size_t)NGRP_PAD * 2048 * 2);
  ushort* hl = (ushort*)alloc((size_t)NGRP_PAD * 2048 * 2);
  ushort* Wph = (ushort*)alloc((size_t)IND * HID * 2);
  ushort* Wpl = (ushort*)alloc((size_t)IND * HID * 2);
  ushort* Relh = (ushort*)alloc((size_t)NLAY * NMAT * HID * HID * 2);
  ushort* Rell = (ushort*)alloc((size_t)NLAY * NMAT * HID * HID * 2);

  size_t used = (size_t)(w - (char*)d_ws);
  size_t rem = (ws_size > used) ? ws_size - used : 0;
  int G = 1;
  if (rem >= (size_t)NN * 10 * HID * 2) G = 10;
  else if (rem >= (size_t)NN * 5 * HID * 2) G = 5;
  else if (rem >= (size_t)NN * 2 * HID * 2) G = 2;
  ushort* T = (ushort*)alloc((size_t)NN * G * HID * 2);
  const int P = NREL / G;

  const int NB_E = (NE + 255) / 256;
  const int NB_N = (NN + 255) / 256;
  const int MB = (NN + 127) / 128;  // 391
  const int ZSPAN = (int)((zend - (char*)winv) / 4);

  zero_kernel<<<dim3(1024), dim3(256), 0, stream>>>(winv, ZSPAN);
  zero_kernel<<<dim3(32), dim3(256), 0, stream>>>(out, NG * HID);

  count_edges<<<dim3(NB_E), dim3(256), 0, stream>>>(dstv, et, winv, deg);
  invert_winv<<<dim3((NN * NREL + 255) / 256), dim3(256), 0, stream>>>(winv);
  scan_block<<<dim3(NB_N), dim3(256), 0, stream>>>(deg, rowstart, partial);
  scan_partials<<<dim3(1), dim3(256), 0, stream>>>(partial, NB_N);
  scan_add<<<dim3(NB_N), dim3(256), 0, stream>>>(rowstart, partial);
  fill_csr<<<dim3(NB_E), dim3(256), 0, stream>>>(dstv, srcv, et, fillpos, rowstart,
                                                 winv, pkd, wsc);

  transpose_split_frag<<<dim3((IND * HID + 255) / 256), dim3(256), 0, stream>>>(
      Wp, Wph, Wpl, 1, IND, 1, 1, 0);
  transpose_split_frag<<<dim3((NLAY * NREL * HID * HID + 255) / 256), dim3(256), 0, stream>>>(
      rel_w, Relh, Rell, NLAY * NREL, HID, NREL, NMAT, 0);
  transpose_split_frag<<<dim3((NLAY * HID * HID + 255) / 256), dim3(256), 0, stream>>>(
      root_w, Relh, Rell, NLAY, HID, 1, NMAT, NREL);

  split_frag<IND><<<dim3(NGRP), dim3(256), 0, stream>>>(x, xh, xl);

  // projection: h = x @ Wp + bp  (bx==0==nrel -> fp32+bias path)
  gemm_frag<IND><<<dim3(1, MB), dim3(256), 0, stream>>>(
      xh, xl, Wph, Wpl, bp, h, (ushort*)nullptr, 128, NN, 0);
  split_frag<HID><<<dim3(NGRP), dim3(256), 0, stream>>>(h, hh, hl);

  for (int l = 0; l < NLAY; ++l) {
    const ushort* Bh = Relh + (size_t)l * NMAT * HID * HID;
    const ushort* Bl = Rell + (size_t)l * NMAT * HID * HID;
    if (G == NREL) {
      gemm_frag<HID><<<dim3(NREL + 1, MB), dim3(256), 0, stream>>>(
          hh, hl, Bh, Bl, conv_b + (size_t)l * HID, OUT, T, G * HID, NN, NREL);
      agg_ln<<<dim3(NGRP), dim3(256), 0, stream>>>(
          pkd, wsc, rowstart, T, OUT, h, ln_g + (size_t)l * HID, ln_b + (size_t)l * HID,
          hh, hl, (l != NLAY - 1) ? 1 : 0);
    } else {
      gemm_frag<HID><<<dim3(1, MB), dim3(256), 0, stream>>>(
          hh, hl, Bh + (size_t)NREL * HID * HID, Bl + (size_t)NREL * HID * HID,
          conv_b + (size_t)l * HID, OUT, (ushort*)nullptr, 128, NN, 0);
      for (int p = 0; p < P; ++p) {
        gemm_frag<HID><<<dim3(G, MB), dim3(256), 0, stream>>>(
            hh, hl, Bh + (size_t)p * G * HID * HID, Bl + (size_t)p * G * HID * HID,
            (const float*)nullptr, (float*)nullptr, T, G * HID, NN, -1);
        aggregate<<<dim3(NN / 4), dim3(256), 0, stream>>>(pkd, wsc, rowstart, T, OUT,
                                                          p * G, G);
      }
      ln_relu_res_frag<<<dim3(NGRP), dim3(256), 0, stream>>>(
          OUT, h, ln_g + (size_t)l * HID, ln_b + (size_t)l * HID, hh, hl);
    }
  }

  pool_kernel<<<dim3((NN + 63) / 64), dim3(128), 0, stream>>>(h, batch, out);
}